// Round 7
// baseline (326.156 us; speedup 1.0000x reference)
//
#include <hip/hip_runtime.h>

#define NUMA 5
#define NCLS 80
#define AL 85          // 80 + 4 + 1
#define HW 361         // 19*19
#define NBOX 1805      // 5*361
#define NBATCH 128
#define NPAD 2048
#define K2T 256
#define MCAP 1024      // register-path cap on num_obj (expected ~902 +/- 21)
#define NCHUNK 16      // MCAP / 64

// ---- d_ws layout (phase-split path) ----
#define WS_NUMOBJ_OFF 0                                  // int32 [128]
#define WS_ORDER_OFF  512                                // u16   [128][2048]
#define WS_SOBJ_OFF   (512 + NBATCH * NPAD * 2)          // f32   [128][2048]
#define WS_NEEDED     ((size_t)(WS_SOBJ_OFF + NBATCH * NPAD * 4))   // ~1.5 MB

__device__ __forceinline__ float bcast_lane(float v, int t) {
    return __uint_as_float(
        (unsigned)__builtin_amdgcn_readlane((int)__float_as_uint(v), t));
}

// ---------------------------------------------------------------------------
// Kernel 1: decode.  pred [B, 425, 19, 19] -> det [B, 1805, 7] written to out
// ---------------------------------------------------------------------------
__global__ __launch_bounds__(256) void decode_kernel(
    const float* __restrict__ pred,
    const float* __restrict__ anchors,
    float* __restrict__ det)
{
#pragma clang fp contract(off)
    int id = blockIdx.x * blockDim.x + threadIdx.x;
    if (id >= NBATCH * NBOX) return;
    int b = id / NBOX;
    int r = id - b * NBOX;
    int a = r / HW;
    int s = r - a * HW;
    int ci = s % 19;
    int cj = s / 19;

    const float* base = pred + ((size_t)(b * (NUMA * AL) + a * AL) * HW + s);
    float tx  = base[0 * HW];
    float ty  = base[1 * HW];
    float tw  = base[2 * HW];
    float th  = base[3 * HW];
    float obj = base[4 * HW];

    float cmax = base[5 * HW];
    int karg = 0;
#pragma unroll 4
    for (int k = 1; k < NCLS; ++k) {
        float c = base[(5 + k) * HW];
        if (c > cmax) { cmax = c; karg = k; }
    }

    float bx = (tx + (float)ci) / 19.0f;
    float by = (ty + (float)cj) / 19.0f;
    float aw = anchors[2 * a];
    float ah = anchors[2 * a + 1];
    float bw = expf(tw) * (aw / 19.0f);
    float bh = expf(th) * (ah / 19.0f);
    float prob = cmax * obj;
    float cid  = (float)karg;

    float* o = det + (size_t)(b * NBOX + r) * 7;
    o[0] = obj; o[1] = bx; o[2] = by; o[3] = bw; o[4] = bh; o[5] = cid; o[6] = prob;
}

// ---------------------------------------------------------------------------
// Kernel 2: per-image stable bitonic sort (desc by obj). 1024 threads/image.
// ---------------------------------------------------------------------------
__global__ __launch_bounds__(1024) void sort_kernel(
    const float* __restrict__ det,
    unsigned short* __restrict__ order_g,
    float* __restrict__ sobj_g,
    int* __restrict__ nobj_g)
{
    __shared__ unsigned long long keys[NPAD];
    __shared__ int cnt_sh;
    const int b = blockIdx.x;
    const int tid = threadIdx.x;
    const float* detb = det + (size_t)b * NBOX * 7;

    for (int n = tid; n < NPAD; n += 1024) {
        keys[n] = (n < NBOX)
            ? (((unsigned long long)__float_as_uint(detb[n * 7]) << 32)
               | (unsigned long long)(2047 - n))
            : 0ull;
    }
    if (tid == 0) cnt_sh = 0;
    __syncthreads();

    for (unsigned k = 2; k <= NPAD; k <<= 1) {
        for (unsigned j = k >> 1; j > 0; j >>= 1) {
            for (unsigned idx = tid; idx < NPAD; idx += 1024) {
                unsigned ixj = idx ^ j;
                if (ixj > idx) {
                    unsigned long long av = keys[idx], bv = keys[ixj];
                    bool up = ((idx & k) == 0);
                    if (up ? (av < bv) : (av > bv)) { keys[idx] = bv; keys[ixj] = av; }
                }
            }
            __syncthreads();
        }
    }

    int cnt = 0;
    for (int r = tid; r < NBOX; r += 1024) {
        unsigned long long kk = keys[r];
        order_g[b * NPAD + r] = (unsigned short)(2047u - (unsigned)(kk & 0xffffffffu));
        float ob = __uint_as_float((unsigned)(kk >> 32));
        sobj_g[b * NPAD + r] = ob;
        cnt += (ob > 0.5f) ? 1 : 0;
    }
    atomicAdd(&cnt_sh, cnt);
    __syncthreads();
    if (tid == 0) nobj_g[b] = cnt_sh;
}

// ---------------------------------------------------------------------------
// Per-chunk greedy NMS step, CC is a COMPILE-TIME chunk index so that every
// access to the register arrays q[]/ar[] is statically indexed after
// inlining (rule #20: dynamic indexing would demote them to scratch --
// rounds 5/6 showed #pragma unroll is silently declined around a nested
// while, so the unroll is forced structurally via 16 template instances).
// ---------------------------------------------------------------------------
template<int CC>
__device__ __forceinline__ void nms_chunk(
    float4 (&q)[NCHUNK], float (&ar)[NCHUNK],
    unsigned& rm_bits, const int M, const int lane)
{
#pragma clang fp contract(off)
    if (CC * 64 < M) {                            // wave-uniform
        const int rem_in = M - CC * 64;
        const unsigned long long chunkmask =
            (rem_in >= 64) ? ~0ull : ((1ull << rem_in) - 1ull);
        unsigned long long wc = __ballot((rm_bits >> CC) & 1u);
        unsigned long long remaining = chunkmask & ~wc;
        while (remaining) {
            int t = (int)__builtin_ctzll(remaining);    // uniform (SGPR)
            // broadcast suppressor box from lane t (registers only)
            float xi1 = bcast_lane(q[CC].x, t);
            float yi1 = bcast_lane(q[CC].y, t);
            float xi2 = bcast_lane(q[CC].z, t);
            float yi2 = bcast_lane(q[CC].w, t);
            float ai  = bcast_lane(ar[CC],  t);
            // --- diagonal: does box t suppress lane's chunk-CC box? ---
            float iw = fmaxf(fminf(q[CC].z, xi2) - fmaxf(q[CC].x, xi1), 0.0f);
            float ih = fmaxf(fminf(q[CC].w, yi2) - fmaxf(q[CC].y, yi1), 0.0f);
            float inter = iw * ih;
            float iou = inter / ((ar[CC] + ai) - inter);     // exact ref arith
            bool supp = (iou >= 0.45f) && (lane > t);
            unsigned long long bb = __ballot(supp);
            rm_bits |= supp ? (1u << CC) : 0u;
            remaining &= ~bb;
            remaining &= ~((t >= 63) ? ~0ull : ((1ull << (t + 1)) - 1ull));
            // --- off-diagonal chunks: register-only, branchless ---
#pragma unroll
            for (int c2 = CC + 1; c2 < NCHUNK; ++c2) {
                float iw2 = fmaxf(fminf(q[c2].z, xi2) - fmaxf(q[c2].x, xi1), 0.0f);
                float ih2 = fmaxf(fminf(q[c2].w, yi2) - fmaxf(q[c2].y, yi1), 0.0f);
                float in2 = iw2 * ih2;
                float iou2 = in2 / ((ar[c2] + ai) - in2);
                rm_bits |= (iou2 >= 0.45f) ? (1u << c2) : 0u;
            }
        }
    }
}

// ---------------------------------------------------------------------------
// Kernel 3: greedy NMS. ONE wave per image, zero LDS, all 1024 boxes in
// registers (16 chunks x 64 lanes). Sentinels (rank >= M) give iou = 0.
// ---------------------------------------------------------------------------
__global__ __launch_bounds__(64, 1) void nms3_kernel(
    const float* __restrict__ det,
    const unsigned short* __restrict__ order_g,
    float* __restrict__ sobj_g,
    const int* __restrict__ nobj_g)
{
#pragma clang fp contract(off)
    const int b = blockIdx.x;
    const int lane = threadIdx.x;
    const float* detb = det + (size_t)b * NBOX * 7;
    const unsigned short* ord = order_g + b * NPAD;
    float* sobj = sobj_g + b * NPAD;
    const int num_obj = nobj_g[b];
    const int M = (num_obj < MCAP) ? num_obj : MCAP;

    if (num_obj <= MCAP) {
        // --- load lane-local boxes straight into registers (static index) ---
        float4 q[NCHUNK];
        float  ar[NCHUNK];
#pragma unroll
        for (int c = 0; c < NCHUNK; ++c) {
            int r = c * 64 + lane;
            if (r < M) {
                const float* row = detb + (int)ord[r] * 7;
                float bx = row[1], by = row[2], bw = row[3], bh = row[4];
                q[c] = make_float4(bx - 0.5f * bw, by - 0.5f * bh,
                                   bx + 0.5f * bw, by + 0.5f * bh);
                ar[c] = bw * bh;
            } else {
                q[c] = make_float4(3e9f, 3e9f, 3.0000001e9f, 3.0000001e9f);
                ar[c] = 1.0f;
            }
        }

        unsigned rm_bits = 0u;    // bit c = this lane's box in chunk c removed
        nms_chunk<0>(q, ar, rm_bits, M, lane);
        nms_chunk<1>(q, ar, rm_bits, M, lane);
        nms_chunk<2>(q, ar, rm_bits, M, lane);
        nms_chunk<3>(q, ar, rm_bits, M, lane);
        nms_chunk<4>(q, ar, rm_bits, M, lane);
        nms_chunk<5>(q, ar, rm_bits, M, lane);
        nms_chunk<6>(q, ar, rm_bits, M, lane);
        nms_chunk<7>(q, ar, rm_bits, M, lane);
        nms_chunk<8>(q, ar, rm_bits, M, lane);
        nms_chunk<9>(q, ar, rm_bits, M, lane);
        nms_chunk<10>(q, ar, rm_bits, M, lane);
        nms_chunk<11>(q, ar, rm_bits, M, lane);
        nms_chunk<12>(q, ar, rm_bits, M, lane);
        nms_chunk<13>(q, ar, rm_bits, M, lane);
        nms_chunk<14>(q, ar, rm_bits, M, lane);
        nms_chunk<15>(q, ar, rm_bits, M, lane);

        // --- write removals ---
#pragma unroll
        for (int c2 = 0; c2 < NCHUNK; ++c2) {
            int j = c2 * 64 + lane;
            if (j < M && ((rm_bits >> c2) & 1u)) sobj[j] = 0.0f;
        }
    } else {
        // fallback (num_obj > 1024; statistically unreachable): serial greedy
        for (int i = 0; i < num_obj; ++i) {
            if (sobj[i] > 0.01f) {
                const float* ri = detb + (int)ord[i] * 7;
                float bxi = ri[1], byi = ri[2], bwi = ri[3], bhi = ri[4];
                float xi1 = bxi - 0.5f * bwi, xi2 = bxi + 0.5f * bwi;
                float yi1 = byi - 0.5f * bhi, yi2 = byi + 0.5f * bhi;
                float ai = bwi * bhi;
                for (int j = i + 1 + lane; j < num_obj; j += 64) {
                    const float* rj = detb + (int)ord[j] * 7;
                    float bxj = rj[1], byj = rj[2], bwj = rj[3], bhj = rj[4];
                    float x1j = bxj - 0.5f * bwj, x2j = bxj + 0.5f * bwj;
                    float y1j = byj - 0.5f * bhj, y2j = byj + 0.5f * bhj;
                    float aj = bwj * bhj;
                    float iw = fmaxf(fminf(x2j, xi2) - fmaxf(x1j, xi1), 0.0f);
                    float ih = fmaxf(fminf(y2j, yi2) - fmaxf(y1j, yi1), 0.0f);
                    float inter = iw * ih;
                    float iou = inter / ((aj + ai) - inter);
                    if (iou >= 0.45f) sobj[j] = 0.0f;
                }
            }
            __syncthreads();
        }
    }
}

// ---------------------------------------------------------------------------
// Kernel 4: epilogue. Gather rows in sorted order, apply filters, write det
// in place (all reads before barrier, all writes after).
// ---------------------------------------------------------------------------
__global__ __launch_bounds__(256) void epi_kernel(
    float* __restrict__ det,
    const unsigned short* __restrict__ order_g,
    const float* __restrict__ sobj_g,
    const int* __restrict__ nobj_g)
{
#pragma clang fp contract(off)
    const int b = blockIdx.x;
    const int tid = threadIdx.x;
    float* detb = det + (size_t)b * NBOX * 7;
    const unsigned short* ord = order_g + b * NPAD;
    const float* sobj = sobj_g + b * NPAD;
    const int num_obj = nobj_g[b];

    float v0[8], v1[8], v2[8], v3[8], v4[8], v5[8], v6[8], msk[8];
#pragma unroll
    for (int c = 0; c < 8; ++c) {
        int r = tid + c * 256;
        if (r < NBOX) {
            const float* row = detb + (int)ord[r] * 7;
            float obj = row[0], bx = row[1], by = row[2], bw = row[3];
            float bh = row[4], cid = row[5], prob = row[6];
            bool keep = (r < num_obj) && (sobj[r] > 0.01f) && (r != num_obj - 1);
            float p = prob * ((prob > 0.1f) ? 1.0f : 0.0f);
            bool fin = keep && (p > 0.01f) && (bw * bw > 0.0004f);
            v0[c] = obj; v1[c] = bx; v2[c] = by; v3[c] = bw; v4[c] = bh;
            v5[c] = cid; v6[c] = p;
            msk[c] = fin ? 1.0f : 0.0f;
        }
    }
    __syncthreads();
#pragma unroll
    for (int c = 0; c < 8; ++c) {
        int r = tid + c * 256;
        if (r < NBOX) {
            float* o = detb + r * 7;
            o[0] = v0[c] * msk[c];
            o[1] = v1[c] * msk[c];
            o[2] = v2[c] * msk[c];
            o[3] = v3[c] * msk[c];
            o[4] = v4[c] * msk[c];
            o[5] = v5[c] * msk[c];
            o[6] = v6[c] * msk[c];
        }
    }
}

// ---------------------------------------------------------------------------
// Fallback monolithic kernel (used only if ws_size < WS_NEEDED).
// ---------------------------------------------------------------------------
__global__ __launch_bounds__(K2T, 1) void nms_kernel(float* __restrict__ det)
{
#pragma clang fp contract(off)
    __shared__ alignas(16) union {
        unsigned long long keys[NPAD];
        struct { float4 q[MCAP]; float area[MCAP]; } box;
    } U;
    __shared__ float s_obj[NBOX];
    __shared__ unsigned short order[NBOX];
    __shared__ int num_obj_sh;

    const int b = blockIdx.x;
    const int tid = threadIdx.x;
    float* detb = det + (size_t)b * NBOX * 7;

    for (int n = tid; n < NPAD; n += K2T) {
        if (n < NBOX) {
            unsigned ob = __float_as_uint(detb[n * 7 + 0]);
            U.keys[n] = ((unsigned long long)ob << 32) | (unsigned long long)(2047 - n);
        } else U.keys[n] = 0ull;
    }
    if (tid == 0) num_obj_sh = 0;
    __syncthreads();

    for (unsigned k = 2; k <= NPAD; k <<= 1) {
        for (unsigned j = k >> 1; j > 0; j >>= 1) {
            for (unsigned idx = tid; idx < NPAD; idx += K2T) {
                unsigned ixj = idx ^ j;
                if (ixj > idx) {
                    unsigned long long av = U.keys[idx], bv = U.keys[ixj];
                    bool up = ((idx & k) == 0);
                    if (up ? (av < bv) : (av > bv)) { U.keys[idx] = bv; U.keys[ixj] = av; }
                }
            }
            __syncthreads();
        }
    }

    int cnt = 0;
    for (int r = tid; r < NBOX; r += K2T) {
        unsigned long long kk = U.keys[r];
        order[r] = (unsigned short)(2047u - (unsigned)(kk & 0xffffffffu));
        float ob = __uint_as_float((unsigned)(kk >> 32));
        s_obj[r] = ob;
        cnt += (ob > 0.5f) ? 1 : 0;
    }
    atomicAdd(&num_obj_sh, cnt);
    __syncthreads();
    const int num_obj = num_obj_sh;

    for (int i = 0; i < num_obj; ++i) {
        if (s_obj[i] > 0.01f) {
            const float* ri = detb + (int)order[i] * 7;
            float bxi = ri[1], byi = ri[2], bwi = ri[3], bhi = ri[4];
            float xi1 = bxi - 0.5f * bwi, xi2 = bxi + 0.5f * bwi;
            float yi1 = byi - 0.5f * bhi, yi2 = byi + 0.5f * bhi;
            float ai = bwi * bhi;
            for (int j = i + 1 + tid; j < num_obj; j += K2T) {
                const float* rj = detb + (int)order[j] * 7;
                float bxj = rj[1], byj = rj[2], bwj = rj[3], bhj = rj[4];
                float x1j = bxj - 0.5f * bwj, x2j = bxj + 0.5f * bwj;
                float y1j = byj - 0.5f * bhj, y2j = byj + 0.5f * bhj;
                float aj = bwj * bhj;
                float iw = fmaxf(fminf(x2j, xi2) - fmaxf(x1j, xi1), 0.0f);
                float ih = fmaxf(fminf(y2j, yi2) - fmaxf(y1j, yi1), 0.0f);
                float inter = iw * ih;
                float iou = inter / ((aj + ai) - inter);
                if (iou >= 0.45f) s_obj[j] = 0.0f;
            }
        }
        __syncthreads();
    }

    float v0[8], v1[8], v2[8], v3[8], v4[8], v5[8], v6[8], msk[8];
#pragma unroll
    for (int c = 0; c < 8; ++c) {
        int r = tid + c * K2T;
        if (r < NBOX) {
            const float* row = detb + (int)order[r] * 7;
            float obj = row[0], bx = row[1], by = row[2], bw = row[3];
            float bh = row[4], cid = row[5], prob = row[6];
            bool keep = (r < num_obj) && (s_obj[r] > 0.01f) && (r != num_obj - 1);
            float p = prob * ((prob > 0.1f) ? 1.0f : 0.0f);
            bool fin = keep && (p > 0.01f) && (bw * bw > 0.0004f);
            v0[c] = obj; v1[c] = bx; v2[c] = by; v3[c] = bw; v4[c] = bh;
            v5[c] = cid; v6[c] = p;
            msk[c] = fin ? 1.0f : 0.0f;
        }
    }
    __syncthreads();
#pragma unroll
    for (int c = 0; c < 8; ++c) {
        int r = tid + c * K2T;
        if (r < NBOX) {
            float* o = detb + r * 7;
            o[0] = v0[c] * msk[c]; o[1] = v1[c] * msk[c]; o[2] = v2[c] * msk[c];
            o[3] = v3[c] * msk[c]; o[4] = v4[c] * msk[c]; o[5] = v5[c] * msk[c];
            o[6] = v6[c] * msk[c];
        }
    }
}

extern "C" void kernel_launch(void* const* d_in, const int* in_sizes, int n_in,
                              void* d_out, int out_size, void* d_ws, size_t ws_size,
                              hipStream_t stream)
{
    const float* pred    = (const float*)d_in[0];
    const float* anchors = (const float*)d_in[1];
    float* out = (float*)d_out;

    int total = NBATCH * NBOX;
    int blocks = (total + 255) / 256;
    decode_kernel<<<blocks, 256, 0, stream>>>(pred, anchors, out);

    if (ws_size >= WS_NEEDED) {
        char* ws = (char*)d_ws;
        int*            nobj  = (int*)(ws + WS_NUMOBJ_OFF);
        unsigned short* order = (unsigned short*)(ws + WS_ORDER_OFF);
        float*          sobj  = (float*)(ws + WS_SOBJ_OFF);
        sort_kernel<<<NBATCH, 1024, 0, stream>>>(out, order, sobj, nobj);
        nms3_kernel<<<NBATCH, 64, 0, stream>>>(out, order, sobj, nobj);
        epi_kernel<<<NBATCH, 256, 0, stream>>>(out, order, sobj, nobj);
    } else {
        nms_kernel<<<NBATCH, K2T, 0, stream>>>(out);
    }
}

// Round 8
// 317.628 us; speedup vs baseline: 1.0268x; 1.0268x over previous
//
#include <hip/hip_runtime.h>

#define NUMA 5
#define NCLS 80
#define AL 85          // 80 + 4 + 1
#define HW 361         // 19*19
#define NBOX 1805      // 5*361
#define NBATCH 128
#define NPAD 2048
#define K2T 256
#define MCAP 1024      // register-path cap on num_obj (expected ~902 +/- 21)
#define NCHUNK 16      // MCAP / 64

// ---- d_ws layout (phase-split path) ----
#define WS_NUMOBJ_OFF 0                                  // int32 [128]
#define WS_ORDER_OFF  512                                // u16   [128][2048]
#define WS_SOBJ_OFF   (512 + NBATCH * NPAD * 2)          // f32   [128][2048]
#define WS_NEEDED     ((size_t)(WS_SOBJ_OFF + NBATCH * NPAD * 4))   // ~1.5 MB

__device__ __forceinline__ float bcast_lane(float v, int t) {
    return __uint_as_float(
        (unsigned)__builtin_amdgcn_readlane((int)__float_as_uint(v), t));
}

// ---------------------------------------------------------------------------
// Kernel 1: decode.  pred [B, 425, 19, 19] -> det [B, 1805, 7] written to out
// ---------------------------------------------------------------------------
__global__ __launch_bounds__(256) void decode_kernel(
    const float* __restrict__ pred,
    const float* __restrict__ anchors,
    float* __restrict__ det)
{
#pragma clang fp contract(off)
    int id = blockIdx.x * blockDim.x + threadIdx.x;
    if (id >= NBATCH * NBOX) return;
    int b = id / NBOX;
    int r = id - b * NBOX;
    int a = r / HW;
    int s = r - a * HW;
    int ci = s % 19;
    int cj = s / 19;

    const float* base = pred + ((size_t)(b * (NUMA * AL) + a * AL) * HW + s);
    float tx  = base[0 * HW];
    float ty  = base[1 * HW];
    float tw  = base[2 * HW];
    float th  = base[3 * HW];
    float obj = base[4 * HW];

    float cmax = base[5 * HW];
    int karg = 0;
#pragma unroll 4
    for (int k = 1; k < NCLS; ++k) {
        float c = base[(5 + k) * HW];
        if (c > cmax) { cmax = c; karg = k; }
    }

    float bx = (tx + (float)ci) / 19.0f;
    float by = (ty + (float)cj) / 19.0f;
    float aw = anchors[2 * a];
    float ah = anchors[2 * a + 1];
    float bw = expf(tw) * (aw / 19.0f);
    float bh = expf(th) * (ah / 19.0f);
    float prob = cmax * obj;
    float cid  = (float)karg;

    float* o = det + (size_t)(b * NBOX + r) * 7;
    o[0] = obj; o[1] = bx; o[2] = by; o[3] = bw; o[4] = bh; o[5] = cid; o[6] = prob;
}

// ---------------------------------------------------------------------------
// Kernel 2: per-image stable bitonic sort (desc by obj). 1024 threads/image.
// ---------------------------------------------------------------------------
__global__ __launch_bounds__(1024) void sort_kernel(
    const float* __restrict__ det,
    unsigned short* __restrict__ order_g,
    float* __restrict__ sobj_g,
    int* __restrict__ nobj_g)
{
    __shared__ unsigned long long keys[NPAD];
    __shared__ int cnt_sh;
    const int b = blockIdx.x;
    const int tid = threadIdx.x;
    const float* detb = det + (size_t)b * NBOX * 7;

    for (int n = tid; n < NPAD; n += 1024) {
        keys[n] = (n < NBOX)
            ? (((unsigned long long)__float_as_uint(detb[n * 7]) << 32)
               | (unsigned long long)(2047 - n))
            : 0ull;
    }
    if (tid == 0) cnt_sh = 0;
    __syncthreads();

    for (unsigned k = 2; k <= NPAD; k <<= 1) {
        for (unsigned j = k >> 1; j > 0; j >>= 1) {
            for (unsigned idx = tid; idx < NPAD; idx += 1024) {
                unsigned ixj = idx ^ j;
                if (ixj > idx) {
                    unsigned long long av = keys[idx], bv = keys[ixj];
                    bool up = ((idx & k) == 0);
                    if (up ? (av < bv) : (av > bv)) { keys[idx] = bv; keys[ixj] = av; }
                }
            }
            __syncthreads();
        }
    }

    int cnt = 0;
    for (int r = tid; r < NBOX; r += 1024) {
        unsigned long long kk = keys[r];
        order_g[b * NPAD + r] = (unsigned short)(2047u - (unsigned)(kk & 0xffffffffu));
        float ob = __uint_as_float((unsigned)(kk >> 32));
        sobj_g[b * NPAD + r] = ob;
        cnt += (ob > 0.5f) ? 1 : 0;
    }
    atomicAdd(&cnt_sh, cnt);
    __syncthreads();
    if (tid == 0) nobj_g[b] = cnt_sh;
}

// ---------------------------------------------------------------------------
// Kernel 3: greedy NMS. ONE wave per image, zero LDS, all 1024 boxes held in
// 80 INDIVIDUALLY-NAMED scalar registers (q0..q15 float4 + a0..a15 float).
// No arrays exist in the kernel, so no scratch demotion is possible (rounds
// 5-7: both #pragma unroll and template unrolling failed to prevent the
// compiler from putting q[16]/ar[16] in scratch; VGPR stayed 64, 265us of
// scratch-reload stalls at VALUBusy 10%). Chunk bodies are macro-generated.
// Sentinel boxes (rank >= M) give iou = 0 against any real box.
// ---------------------------------------------------------------------------
#define LOADC(CI, QV, AV)                                                  \
    {                                                                      \
        int r = (CI) * 64 + lane;                                          \
        if (r < M) {                                                       \
            const float* row = detb + (int)ord[r] * 7;                     \
            float bx = row[1], by = row[2], bw = row[3], bh = row[4];      \
            QV = make_float4(bx - 0.5f * bw, by - 0.5f * bh,               \
                             bx + 0.5f * bw, by + 0.5f * bh);              \
            AV = bw * bh;                                                  \
        } else {                                                           \
            QV = make_float4(3e9f, 3e9f, 3.0000001e9f, 3.0000001e9f);      \
            AV = 1.0f;                                                     \
        }                                                                  \
    }

#define OFFD(C2, QV, AV)                                                   \
    {                                                                      \
        float iw2 = fmaxf(fminf(QV.z, xi2) - fmaxf(QV.x, xi1), 0.0f);      \
        float ih2 = fmaxf(fminf(QV.w, yi2) - fmaxf(QV.y, yi1), 0.0f);      \
        float in2 = iw2 * ih2;                                             \
        float iou2 = in2 / ((AV + ai) - in2);                              \
        rm_bits |= (iou2 >= 0.45f) ? (1u << (C2)) : 0u;                    \
    }

#define CHUNK(CC, QD, AD, OFFS)                                            \
    if ((CC) * 64 < M) {                                                   \
        const int rem_in = M - (CC) * 64;                                  \
        const unsigned long long chunkmask =                               \
            (rem_in >= 64) ? ~0ull : ((1ull << rem_in) - 1ull);            \
        unsigned long long wc = __ballot((rm_bits >> (CC)) & 1u);          \
        unsigned long long remaining = chunkmask & ~wc;                    \
        while (remaining) {                                                \
            int t = (int)__builtin_ctzll(remaining);                       \
            float xi1 = bcast_lane(QD.x, t);                               \
            float yi1 = bcast_lane(QD.y, t);                               \
            float xi2 = bcast_lane(QD.z, t);                               \
            float yi2 = bcast_lane(QD.w, t);                               \
            float ai  = bcast_lane(AD,   t);                               \
            float iw = fmaxf(fminf(QD.z, xi2) - fmaxf(QD.x, xi1), 0.0f);   \
            float ih = fmaxf(fminf(QD.w, yi2) - fmaxf(QD.y, yi1), 0.0f);   \
            float inter = iw * ih;                                         \
            float iou = inter / ((AD + ai) - inter);                       \
            bool supp = (iou >= 0.45f) && (lane > t);                      \
            unsigned long long bb = __ballot(supp);                        \
            rm_bits |= supp ? (1u << (CC)) : 0u;                           \
            remaining &= ~bb;                                              \
            remaining &= ~((t >= 63) ? ~0ull : ((1ull << (t + 1)) - 1ull));\
            OFFS                                                           \
        }                                                                  \
    }

#define O15 OFFD(15, q15, a15)
#define O14 OFFD(14, q14, a14) O15
#define O13 OFFD(13, q13, a13) O14
#define O12 OFFD(12, q12, a12) O13
#define O11 OFFD(11, q11, a11) O12
#define O10 OFFD(10, q10, a10) O11
#define O9  OFFD(9,  q9,  a9)  O10
#define O8  OFFD(8,  q8,  a8)  O9
#define O7  OFFD(7,  q7,  a7)  O8
#define O6  OFFD(6,  q6,  a6)  O7
#define O5  OFFD(5,  q5,  a5)  O6
#define O4  OFFD(4,  q4,  a4)  O5
#define O3  OFFD(3,  q3,  a3)  O4
#define O2  OFFD(2,  q2,  a2)  O3
#define O1  OFFD(1,  q1,  a1)  O2

__global__ __launch_bounds__(64, 1) void nms3_kernel(
    const float* __restrict__ det,
    const unsigned short* __restrict__ order_g,
    float* __restrict__ sobj_g,
    const int* __restrict__ nobj_g)
{
#pragma clang fp contract(off)
    const int b = blockIdx.x;
    const int lane = threadIdx.x;
    const float* detb = det + (size_t)b * NBOX * 7;
    const unsigned short* ord = order_g + b * NPAD;
    float* sobj = sobj_g + b * NPAD;
    const int num_obj = nobj_g[b];
    const int M = (num_obj < MCAP) ? num_obj : MCAP;

    if (num_obj <= MCAP) {
        float4 q0, q1, q2, q3, q4, q5, q6, q7, q8, q9, q10, q11, q12, q13, q14, q15;
        float  a0, a1, a2, a3, a4, a5, a6, a7, a8, a9, a10, a11, a12, a13, a14, a15;
        LOADC(0, q0, a0)   LOADC(1, q1, a1)   LOADC(2, q2, a2)   LOADC(3, q3, a3)
        LOADC(4, q4, a4)   LOADC(5, q5, a5)   LOADC(6, q6, a6)   LOADC(7, q7, a7)
        LOADC(8, q8, a8)   LOADC(9, q9, a9)   LOADC(10, q10, a10) LOADC(11, q11, a11)
        LOADC(12, q12, a12) LOADC(13, q13, a13) LOADC(14, q14, a14) LOADC(15, q15, a15)

        unsigned rm_bits = 0u;    // bit c = this lane's box in chunk c removed
        CHUNK(0,  q0,  a0,  O1)
        CHUNK(1,  q1,  a1,  O2)
        CHUNK(2,  q2,  a2,  O3)
        CHUNK(3,  q3,  a3,  O4)
        CHUNK(4,  q4,  a4,  O5)
        CHUNK(5,  q5,  a5,  O6)
        CHUNK(6,  q6,  a6,  O7)
        CHUNK(7,  q7,  a7,  O8)
        CHUNK(8,  q8,  a8,  O9)
        CHUNK(9,  q9,  a9,  O10)
        CHUNK(10, q10, a10, O11)
        CHUNK(11, q11, a11, O12)
        CHUNK(12, q12, a12, O13)
        CHUNK(13, q13, a13, O14)
        CHUNK(14, q14, a14, O15)
        CHUNK(15, q15, a15, )

        // --- write removals ---
#pragma unroll
        for (int c2 = 0; c2 < NCHUNK; ++c2) {
            int j = c2 * 64 + lane;
            if (j < M && ((rm_bits >> c2) & 1u)) sobj[j] = 0.0f;
        }
    } else {
        // fallback (num_obj > 1024; statistically unreachable): serial greedy
        for (int i = 0; i < num_obj; ++i) {
            if (sobj[i] > 0.01f) {
                const float* ri = detb + (int)ord[i] * 7;
                float bxi = ri[1], byi = ri[2], bwi = ri[3], bhi = ri[4];
                float xi1 = bxi - 0.5f * bwi, xi2 = bxi + 0.5f * bwi;
                float yi1 = byi - 0.5f * bhi, yi2 = byi + 0.5f * bhi;
                float ai = bwi * bhi;
                for (int j = i + 1 + lane; j < num_obj; j += 64) {
                    const float* rj = detb + (int)ord[j] * 7;
                    float bxj = rj[1], byj = rj[2], bwj = rj[3], bhj = rj[4];
                    float x1j = bxj - 0.5f * bwj, x2j = bxj + 0.5f * bwj;
                    float y1j = byj - 0.5f * bhj, y2j = byj + 0.5f * bhj;
                    float aj = bwj * bhj;
                    float iw = fmaxf(fminf(x2j, xi2) - fmaxf(x1j, xi1), 0.0f);
                    float ih = fmaxf(fminf(y2j, yi2) - fmaxf(y1j, yi1), 0.0f);
                    float inter = iw * ih;
                    float iou = inter / ((aj + ai) - inter);
                    if (iou >= 0.45f) sobj[j] = 0.0f;
                }
            }
            __syncthreads();
        }
    }
}

// ---------------------------------------------------------------------------
// Kernel 4: epilogue. Gather rows in sorted order, apply filters, write det
// in place (all reads before barrier, all writes after).
// ---------------------------------------------------------------------------
__global__ __launch_bounds__(256) void epi_kernel(
    float* __restrict__ det,
    const unsigned short* __restrict__ order_g,
    const float* __restrict__ sobj_g,
    const int* __restrict__ nobj_g)
{
#pragma clang fp contract(off)
    const int b = blockIdx.x;
    const int tid = threadIdx.x;
    float* detb = det + (size_t)b * NBOX * 7;
    const unsigned short* ord = order_g + b * NPAD;
    const float* sobj = sobj_g + b * NPAD;
    const int num_obj = nobj_g[b];

    float v0[8], v1[8], v2[8], v3[8], v4[8], v5[8], v6[8], msk[8];
#pragma unroll
    for (int c = 0; c < 8; ++c) {
        int r = tid + c * 256;
        if (r < NBOX) {
            const float* row = detb + (int)ord[r] * 7;
            float obj = row[0], bx = row[1], by = row[2], bw = row[3];
            float bh = row[4], cid = row[5], prob = row[6];
            bool keep = (r < num_obj) && (sobj[r] > 0.01f) && (r != num_obj - 1);
            float p = prob * ((prob > 0.1f) ? 1.0f : 0.0f);
            bool fin = keep && (p > 0.01f) && (bw * bw > 0.0004f);
            v0[c] = obj; v1[c] = bx; v2[c] = by; v3[c] = bw; v4[c] = bh;
            v5[c] = cid; v6[c] = p;
            msk[c] = fin ? 1.0f : 0.0f;
        }
    }
    __syncthreads();
#pragma unroll
    for (int c = 0; c < 8; ++c) {
        int r = tid + c * 256;
        if (r < NBOX) {
            float* o = detb + r * 7;
            o[0] = v0[c] * msk[c];
            o[1] = v1[c] * msk[c];
            o[2] = v2[c] * msk[c];
            o[3] = v3[c] * msk[c];
            o[4] = v4[c] * msk[c];
            o[5] = v5[c] * msk[c];
            o[6] = v6[c] * msk[c];
        }
    }
}

// ---------------------------------------------------------------------------
// Fallback monolithic kernel (used only if ws_size < WS_NEEDED).
// ---------------------------------------------------------------------------
__global__ __launch_bounds__(K2T, 1) void nms_kernel(float* __restrict__ det)
{
#pragma clang fp contract(off)
    __shared__ alignas(16) union {
        unsigned long long keys[NPAD];
        struct { float4 q[MCAP]; float area[MCAP]; } box;
    } U;
    __shared__ float s_obj[NBOX];
    __shared__ unsigned short order[NBOX];
    __shared__ int num_obj_sh;

    const int b = blockIdx.x;
    const int tid = threadIdx.x;
    float* detb = det + (size_t)b * NBOX * 7;

    for (int n = tid; n < NPAD; n += K2T) {
        if (n < NBOX) {
            unsigned ob = __float_as_uint(detb[n * 7 + 0]);
            U.keys[n] = ((unsigned long long)ob << 32) | (unsigned long long)(2047 - n);
        } else U.keys[n] = 0ull;
    }
    if (tid == 0) num_obj_sh = 0;
    __syncthreads();

    for (unsigned k = 2; k <= NPAD; k <<= 1) {
        for (unsigned j = k >> 1; j > 0; j >>= 1) {
            for (unsigned idx = tid; idx < NPAD; idx += K2T) {
                unsigned ixj = idx ^ j;
                if (ixj > idx) {
                    unsigned long long av = U.keys[idx], bv = U.keys[ixj];
                    bool up = ((idx & k) == 0);
                    if (up ? (av < bv) : (av > bv)) { U.keys[idx] = bv; U.keys[ixj] = av; }
                }
            }
            __syncthreads();
        }
    }

    int cnt = 0;
    for (int r = tid; r < NBOX; r += K2T) {
        unsigned long long kk = U.keys[r];
        order[r] = (unsigned short)(2047u - (unsigned)(kk & 0xffffffffu));
        float ob = __uint_as_float((unsigned)(kk >> 32));
        s_obj[r] = ob;
        cnt += (ob > 0.5f) ? 1 : 0;
    }
    atomicAdd(&num_obj_sh, cnt);
    __syncthreads();
    const int num_obj = num_obj_sh;

    for (int i = 0; i < num_obj; ++i) {
        if (s_obj[i] > 0.01f) {
            const float* ri = detb + (int)order[i] * 7;
            float bxi = ri[1], byi = ri[2], bwi = ri[3], bhi = ri[4];
            float xi1 = bxi - 0.5f * bwi, xi2 = bxi + 0.5f * bwi;
            float yi1 = byi - 0.5f * bhi, yi2 = byi + 0.5f * bhi;
            float ai = bwi * bhi;
            for (int j = i + 1 + tid; j < num_obj; j += K2T) {
                const float* rj = detb + (int)order[j] * 7;
                float bxj = rj[1], byj = rj[2], bwj = rj[3], bhj = rj[4];
                float x1j = bxj - 0.5f * bwj, x2j = bxj + 0.5f * bwj;
                float y1j = byj - 0.5f * bhj, y2j = byj + 0.5f * bhj;
                float aj = bwj * bhj;
                float iw = fmaxf(fminf(x2j, xi2) - fmaxf(x1j, xi1), 0.0f);
                float ih = fmaxf(fminf(y2j, yi2) - fmaxf(y1j, yi1), 0.0f);
                float inter = iw * ih;
                float iou = inter / ((aj + ai) - inter);
                if (iou >= 0.45f) s_obj[j] = 0.0f;
            }
        }
        __syncthreads();
    }

    float v0[8], v1[8], v2[8], v3[8], v4[8], v5[8], v6[8], msk[8];
#pragma unroll
    for (int c = 0; c < 8; ++c) {
        int r = tid + c * K2T;
        if (r < NBOX) {
            const float* row = detb + (int)order[r] * 7;
            float obj = row[0], bx = row[1], by = row[2], bw = row[3];
            float bh = row[4], cid = row[5], prob = row[6];
            bool keep = (r < num_obj) && (s_obj[r] > 0.01f) && (r != num_obj - 1);
            float p = prob * ((prob > 0.1f) ? 1.0f : 0.0f);
            bool fin = keep && (p > 0.01f) && (bw * bw > 0.0004f);
            v0[c] = obj; v1[c] = bx; v2[c] = by; v3[c] = bw; v4[c] = bh;
            v5[c] = cid; v6[c] = p;
            msk[c] = fin ? 1.0f : 0.0f;
        }
    }
    __syncthreads();
#pragma unroll
    for (int c = 0; c < 8; ++c) {
        int r = tid + c * K2T;
        if (r < NBOX) {
            float* o = detb + r * 7;
            o[0] = v0[c] * msk[c]; o[1] = v1[c] * msk[c]; o[2] = v2[c] * msk[c];
            o[3] = v3[c] * msk[c]; o[4] = v4[c] * msk[c]; o[5] = v5[c] * msk[c];
            o[6] = v6[c] * msk[c];
        }
    }
}

extern "C" void kernel_launch(void* const* d_in, const int* in_sizes, int n_in,
                              void* d_out, int out_size, void* d_ws, size_t ws_size,
                              hipStream_t stream)
{
    const float* pred    = (const float*)d_in[0];
    const float* anchors = (const float*)d_in[1];
    float* out = (float*)d_out;

    int total = NBATCH * NBOX;
    int blocks = (total + 255) / 256;
    decode_kernel<<<blocks, 256, 0, stream>>>(pred, anchors, out);

    if (ws_size >= WS_NEEDED) {
        char* ws = (char*)d_ws;
        int*            nobj  = (int*)(ws + WS_NUMOBJ_OFF);
        unsigned short* order = (unsigned short*)(ws + WS_ORDER_OFF);
        float*          sobj  = (float*)(ws + WS_SOBJ_OFF);
        sort_kernel<<<NBATCH, 1024, 0, stream>>>(out, order, sobj, nobj);
        nms3_kernel<<<NBATCH, 64, 0, stream>>>(out, order, sobj, nobj);
        epi_kernel<<<NBATCH, 256, 0, stream>>>(out, order, sobj, nobj);
    } else {
        nms_kernel<<<NBATCH, K2T, 0, stream>>>(out);
    }
}

// Round 9
// 182.478 us; speedup vs baseline: 1.7874x; 1.7406x over previous
//
#include <hip/hip_runtime.h>

#define NUMA 5
#define NCLS 80
#define AL 85          // 80 + 4 + 1
#define HW 361         // 19*19
#define NBOX 1805      // 5*361
#define NBATCH 128
#define NPAD 2048
#define K2T 256
#define MCAP 1024      // two-phase cap on num_obj (expected ~902 +/- 21)
#define NCHUNK 16      // MCAP / 64

// ---- d_ws layout (phase-split path) ----
#define WS_NUMOBJ_OFF 0                                  // int32 [128]
#define WS_ORDER_OFF  512                                // u16   [128][2048]
#define WS_SOBJ_OFF   (512 + NBATCH * NPAD * 2)          // f32   [128][2048]
#define WS_NEEDED     ((size_t)(WS_SOBJ_OFF + NBATCH * NPAD * 4))   // ~1.5 MB

// Exact-division-compare constant: MID = (0.45f + pred(0.45f))/2 exactly.
// RN32(inter/denom) >= 0.45f  <=>  inter >= denom*MID (real arithmetic)
//                            <=>  fma64(denom, MID, -inter) <= 0   (exact sign:
// 24bit*25bit product minus 24-bit value -> <=50 significant bits, no underflow)
#define MID_CONST (30198987.0 / 67108864.0)

// ---------------------------------------------------------------------------
// Kernel 1: decode.  pred [B, 425, 19, 19] -> det [B, 1805, 7] written to out
// ---------------------------------------------------------------------------
__global__ __launch_bounds__(256) void decode_kernel(
    const float* __restrict__ pred,
    const float* __restrict__ anchors,
    float* __restrict__ det)
{
#pragma clang fp contract(off)
    int id = blockIdx.x * blockDim.x + threadIdx.x;
    if (id >= NBATCH * NBOX) return;
    int b = id / NBOX;
    int r = id - b * NBOX;
    int a = r / HW;
    int s = r - a * HW;
    int ci = s % 19;
    int cj = s / 19;

    const float* base = pred + ((size_t)(b * (NUMA * AL) + a * AL) * HW + s);
    float tx  = base[0 * HW];
    float ty  = base[1 * HW];
    float tw  = base[2 * HW];
    float th  = base[3 * HW];
    float obj = base[4 * HW];

    float cmax = base[5 * HW];
    int karg = 0;
#pragma unroll 4
    for (int k = 1; k < NCLS; ++k) {
        float c = base[(5 + k) * HW];
        if (c > cmax) { cmax = c; karg = k; }
    }

    float bx = (tx + (float)ci) / 19.0f;
    float by = (ty + (float)cj) / 19.0f;
    float aw = anchors[2 * a];
    float ah = anchors[2 * a + 1];
    float bw = expf(tw) * (aw / 19.0f);
    float bh = expf(th) * (ah / 19.0f);
    float prob = cmax * obj;
    float cid  = (float)karg;

    float* o = det + (size_t)(b * NBOX + r) * 7;
    o[0] = obj; o[1] = bx; o[2] = by; o[3] = bw; o[4] = bh; o[5] = cid; o[6] = prob;
}

// ---------------------------------------------------------------------------
// Kernel 2: per-image stable bitonic sort (desc by obj). 1024 threads/image.
// ---------------------------------------------------------------------------
__global__ __launch_bounds__(1024) void sort_kernel(
    const float* __restrict__ det,
    unsigned short* __restrict__ order_g,
    float* __restrict__ sobj_g,
    int* __restrict__ nobj_g)
{
    __shared__ unsigned long long keys[NPAD];
    __shared__ int cnt_sh;
    const int b = blockIdx.x;
    const int tid = threadIdx.x;
    const float* detb = det + (size_t)b * NBOX * 7;

    for (int n = tid; n < NPAD; n += 1024) {
        keys[n] = (n < NBOX)
            ? (((unsigned long long)__float_as_uint(detb[n * 7]) << 32)
               | (unsigned long long)(2047 - n))
            : 0ull;
    }
    if (tid == 0) cnt_sh = 0;
    __syncthreads();

    for (unsigned k = 2; k <= NPAD; k <<= 1) {
        for (unsigned j = k >> 1; j > 0; j >>= 1) {
            for (unsigned idx = tid; idx < NPAD; idx += 1024) {
                unsigned ixj = idx ^ j;
                if (ixj > idx) {
                    unsigned long long av = keys[idx], bv = keys[ixj];
                    bool up = ((idx & k) == 0);
                    if (up ? (av < bv) : (av > bv)) { keys[idx] = bv; keys[ixj] = av; }
                }
            }
            __syncthreads();
        }
    }

    int cnt = 0;
    for (int r = tid; r < NBOX; r += 1024) {
        unsigned long long kk = keys[r];
        order_g[b * NPAD + r] = (unsigned short)(2047u - (unsigned)(kk & 0xffffffffu));
        float ob = __uint_as_float((unsigned)(kk >> 32));
        sobj_g[b * NPAD + r] = ob;
        cnt += (ob > 0.5f) ? 1 : 0;
    }
    atomicAdd(&cnt_sh, cnt);
    __syncthreads();
    if (tid == 0) nobj_g[b] = cnt_sh;
}

// ---------------------------------------------------------------------------
// Kernel 3: two-phase NMS, one block (1024 thr, 148 KB LDS) per image.
// Phase 1 (16 waves, parallel): SUP[cc][r] = bitmask of chunk-cc boxes that
//   would suppress box r (iou >= 0.45 AND earlier rank). 136 (c2,cc<=c2)
//   tiles balanced across waves. Exact div-compare via f64 fma (MID_CONST).
// Phase 2 (wave 0, serial, bit-ops only): greedy scan; within-chunk via
//   ballot of per-lane column words; cross-chunk via survivor-mask AND.
// ---------------------------------------------------------------------------
__global__ __launch_bounds__(1024, 1) void nms4_kernel(
    const float* __restrict__ det,
    const unsigned short* __restrict__ order_g,
    float* __restrict__ sobj_g,
    const int* __restrict__ nobj_g)
{
#pragma clang fp contract(off)
    __shared__ float4 QS[MCAP];                          // 16 KB
    __shared__ float  AS[MCAP];                          // 4 KB
    __shared__ unsigned long long SUP[NCHUNK][MCAP];     // 128 KB
    const int b = blockIdx.x;
    const int tid = threadIdx.x;
    const int lane = tid & 63;
    const int wv = tid >> 6;
    const float* detb = det + (size_t)b * NBOX * 7;
    const unsigned short* ord = order_g + b * NPAD;
    float* sobj = sobj_g + b * NPAD;
    const int num_obj = nobj_g[b];
    const int M = (num_obj < MCAP) ? num_obj : MCAP;

    if (num_obj <= MCAP) {
        // --- stage sorted boxes (ranks 0..1023 all exist; >=M rows unused) ---
        {
            const float* row = detb + (int)ord[tid] * 7;
            float bx = row[1], by = row[2], bw = row[3], bh = row[4];
            QS[tid] = make_float4(bx - 0.5f * bw, by - 0.5f * bh,
                                  bx + 0.5f * bw, by + 0.5f * bh);
            AS[tid] = bw * bh;
        }
        __syncthreads();

        // --- phase 1: build suppression columns ---
        for (int k = wv; k < 136; k += 16) {
            int c2 = 0;
            while ((c2 + 1) * (c2 + 2) / 2 <= k) ++c2;   // tile -> (c2, cc)
            int cc = k - c2 * (c2 + 1) / 2;
            if (c2 * 64 < M) {
                int j = c2 * 64 + lane;
                float4 qj = QS[j];
                float  aj = AS[j];
                unsigned long long w = 0ull;
                for (int t = 0; t < 64; ++t) {
                    int it = cc * 64 + t;
                    float4 qt = QS[it];                  // uniform -> broadcast
                    float  at = AS[it];
                    float iw = fmaxf(fminf(qj.z, qt.z) - fmaxf(qj.x, qt.x), 0.0f);
                    float ih = fmaxf(fminf(qj.w, qt.w) - fmaxf(qj.y, qt.y), 0.0f);
                    float inter = iw * ih;
                    float denom = (aj + at) - inter;     // == ref (a_j+a_i)-inter
                    bool supp = (fma((double)denom, MID_CONST,
                                     -(double)inter) <= 0.0);
                    bool ok = (cc != c2) || (t < lane);  // rank order (t<j)
                    w |= (supp && ok) ? (1ull << t) : 0ull;
                }
                SUP[cc][j] = w;
            }
        }
        __syncthreads();

        // --- phase 2: serial greedy scan (wave 0, no FP, no div) ---
        if (wv == 0) {
            unsigned rm = 0u;                  // bit c = my box in chunk c dead
            for (int c = 0; c < NCHUNK && c * 64 < M; ++c) {
                int rem_in = M - c * 64;
                unsigned long long cmask =
                    (rem_in >= 64) ? ~0ull : ((1ull << rem_in) - 1ull);
                unsigned long long wc = __ballot((rm >> c) & 1u);
                unsigned long long rem = cmask & ~wc;
                unsigned long long myw = SUP[c][c * 64 + lane];
                unsigned long long S = 0ull;   // survivors of chunk c
                while (rem) {
                    int t = (int)__builtin_ctzll(rem);
                    S |= (1ull << t);
                    bool hit = (myw >> t) & 1ull;        // t<lane enforced at build
                    unsigned long long bb = __ballot(hit);
                    rm |= hit ? (1u << c) : 0u;
                    rem &= ~bb;
                    rem &= ~((t >= 63) ? ~0ull : ((1ull << (t + 1)) - 1ull));
                }
                for (int c2 = c + 1; c2 < NCHUNK && c2 * 64 < M; ++c2) {
                    unsigned long long w2 = SUP[c][c2 * 64 + lane];
                    rm |= ((w2 & S) != 0ull) ? (1u << c2) : 0u;
                }
            }
            for (int c2 = 0; c2 < NCHUNK; ++c2) {
                int j = c2 * 64 + lane;
                if (j < M && ((rm >> c2) & 1u)) sobj[j] = 0.0f;
            }
        }
    } else {
        // fallback (num_obj > 1024; statistically unreachable): serial greedy
        for (int i = 0; i < num_obj; ++i) {
            if (sobj[i] > 0.01f) {
                const float* ri = detb + (int)ord[i] * 7;
                float bxi = ri[1], byi = ri[2], bwi = ri[3], bhi = ri[4];
                float xi1 = bxi - 0.5f * bwi, xi2 = bxi + 0.5f * bwi;
                float yi1 = byi - 0.5f * bhi, yi2 = byi + 0.5f * bhi;
                float ai = bwi * bhi;
                for (int j = i + 1 + tid; j < num_obj; j += 1024) {
                    const float* rj = detb + (int)ord[j] * 7;
                    float bxj = rj[1], byj = rj[2], bwj = rj[3], bhj = rj[4];
                    float x1j = bxj - 0.5f * bwj, x2j = bxj + 0.5f * bwj;
                    float y1j = byj - 0.5f * bhj, y2j = byj + 0.5f * bhj;
                    float aj = bwj * bhj;
                    float iw = fmaxf(fminf(x2j, xi2) - fmaxf(x1j, xi1), 0.0f);
                    float ih = fmaxf(fminf(y2j, yi2) - fmaxf(y1j, yi1), 0.0f);
                    float inter = iw * ih;
                    float iou = inter / ((aj + ai) - inter);
                    if (iou >= 0.45f) sobj[j] = 0.0f;
                }
            }
            __syncthreads();
        }
    }
}

// ---------------------------------------------------------------------------
// Kernel 4: epilogue. Gather rows in sorted order, apply filters, write det
// in place (all reads before barrier, all writes after).
// ---------------------------------------------------------------------------
__global__ __launch_bounds__(256) void epi_kernel(
    float* __restrict__ det,
    const unsigned short* __restrict__ order_g,
    const float* __restrict__ sobj_g,
    const int* __restrict__ nobj_g)
{
#pragma clang fp contract(off)
    const int b = blockIdx.x;
    const int tid = threadIdx.x;
    float* detb = det + (size_t)b * NBOX * 7;
    const unsigned short* ord = order_g + b * NPAD;
    const float* sobj = sobj_g + b * NPAD;
    const int num_obj = nobj_g[b];

    float v0[8], v1[8], v2[8], v3[8], v4[8], v5[8], v6[8], msk[8];
#pragma unroll
    for (int c = 0; c < 8; ++c) {
        int r = tid + c * 256;
        if (r < NBOX) {
            const float* row = detb + (int)ord[r] * 7;
            float obj = row[0], bx = row[1], by = row[2], bw = row[3];
            float bh = row[4], cid = row[5], prob = row[6];
            bool keep = (r < num_obj) && (sobj[r] > 0.01f) && (r != num_obj - 1);
            float p = prob * ((prob > 0.1f) ? 1.0f : 0.0f);
            bool fin = keep && (p > 0.01f) && (bw * bw > 0.0004f);
            v0[c] = obj; v1[c] = bx; v2[c] = by; v3[c] = bw; v4[c] = bh;
            v5[c] = cid; v6[c] = p;
            msk[c] = fin ? 1.0f : 0.0f;
        }
    }
    __syncthreads();
#pragma unroll
    for (int c = 0; c < 8; ++c) {
        int r = tid + c * 256;
        if (r < NBOX) {
            float* o = detb + r * 7;
            o[0] = v0[c] * msk[c];
            o[1] = v1[c] * msk[c];
            o[2] = v2[c] * msk[c];
            o[3] = v3[c] * msk[c];
            o[4] = v4[c] * msk[c];
            o[5] = v5[c] * msk[c];
            o[6] = v6[c] * msk[c];
        }
    }
}

// ---------------------------------------------------------------------------
// Fallback monolithic kernel (used only if ws_size < WS_NEEDED).
// ---------------------------------------------------------------------------
__global__ __launch_bounds__(K2T, 1) void nms_kernel(float* __restrict__ det)
{
#pragma clang fp contract(off)
    __shared__ alignas(16) union {
        unsigned long long keys[NPAD];
        struct { float4 q[MCAP]; float area[MCAP]; } box;
    } U;
    __shared__ float s_obj[NBOX];
    __shared__ unsigned short order[NBOX];
    __shared__ int num_obj_sh;

    const int b = blockIdx.x;
    const int tid = threadIdx.x;
    float* detb = det + (size_t)b * NBOX * 7;

    for (int n = tid; n < NPAD; n += K2T) {
        if (n < NBOX) {
            unsigned ob = __float_as_uint(detb[n * 7 + 0]);
            U.keys[n] = ((unsigned long long)ob << 32) | (unsigned long long)(2047 - n);
        } else U.keys[n] = 0ull;
    }
    if (tid == 0) num_obj_sh = 0;
    __syncthreads();

    for (unsigned k = 2; k <= NPAD; k <<= 1) {
        for (unsigned j = k >> 1; j > 0; j >>= 1) {
            for (unsigned idx = tid; idx < NPAD; idx += K2T) {
                unsigned ixj = idx ^ j;
                if (ixj > idx) {
                    unsigned long long av = U.keys[idx], bv = U.keys[ixj];
                    bool up = ((idx & k) == 0);
                    if (up ? (av < bv) : (av > bv)) { U.keys[idx] = bv; U.keys[ixj] = av; }
                }
            }
            __syncthreads();
        }
    }

    int cnt = 0;
    for (int r = tid; r < NBOX; r += K2T) {
        unsigned long long kk = U.keys[r];
        order[r] = (unsigned short)(2047u - (unsigned)(kk & 0xffffffffu));
        float ob = __uint_as_float((unsigned)(kk >> 32));
        s_obj[r] = ob;
        cnt += (ob > 0.5f) ? 1 : 0;
    }
    atomicAdd(&num_obj_sh, cnt);
    __syncthreads();
    const int num_obj = num_obj_sh;

    for (int i = 0; i < num_obj; ++i) {
        if (s_obj[i] > 0.01f) {
            const float* ri = detb + (int)order[i] * 7;
            float bxi = ri[1], byi = ri[2], bwi = ri[3], bhi = ri[4];
            float xi1 = bxi - 0.5f * bwi, xi2 = bxi + 0.5f * bwi;
            float yi1 = byi - 0.5f * bhi, yi2 = byi + 0.5f * bhi;
            float ai = bwi * bhi;
            for (int j = i + 1 + tid; j < num_obj; j += K2T) {
                const float* rj = detb + (int)order[j] * 7;
                float bxj = rj[1], byj = rj[2], bwj = rj[3], bhj = rj[4];
                float x1j = bxj - 0.5f * bwj, x2j = bxj + 0.5f * bwj;
                float y1j = byj - 0.5f * bhj, y2j = byj + 0.5f * bhj;
                float aj = bwj * bhj;
                float iw = fmaxf(fminf(x2j, xi2) - fmaxf(x1j, xi1), 0.0f);
                float ih = fmaxf(fminf(y2j, yi2) - fmaxf(y1j, yi1), 0.0f);
                float inter = iw * ih;
                float iou = inter / ((aj + ai) - inter);
                if (iou >= 0.45f) s_obj[j] = 0.0f;
            }
        }
        __syncthreads();
    }

    float v0[8], v1[8], v2[8], v3[8], v4[8], v5[8], v6[8], msk[8];
#pragma unroll
    for (int c = 0; c < 8; ++c) {
        int r = tid + c * K2T;
        if (r < NBOX) {
            const float* row = detb + (int)order[r] * 7;
            float obj = row[0], bx = row[1], by = row[2], bw = row[3];
            float bh = row[4], cid = row[5], prob = row[6];
            bool keep = (r < num_obj) && (s_obj[r] > 0.01f) && (r != num_obj - 1);
            float p = prob * ((prob > 0.1f) ? 1.0f : 0.0f);
            bool fin = keep && (p > 0.01f) && (bw * bw > 0.0004f);
            v0[c] = obj; v1[c] = bx; v2[c] = by; v3[c] = bw; v4[c] = bh;
            v5[c] = cid; v6[c] = p;
            msk[c] = fin ? 1.0f : 0.0f;
        }
    }
    __syncthreads();
#pragma unroll
    for (int c = 0; c < 8; ++c) {
        int r = tid + c * K2T;
        if (r < NBOX) {
            float* o = detb + r * 7;
            o[0] = v0[c] * msk[c]; o[1] = v1[c] * msk[c]; o[2] = v2[c] * msk[c];
            o[3] = v3[c] * msk[c]; o[4] = v4[c] * msk[c]; o[5] = v5[c] * msk[c];
            o[6] = v6[c] * msk[c];
        }
    }
}

extern "C" void kernel_launch(void* const* d_in, const int* in_sizes, int n_in,
                              void* d_out, int out_size, void* d_ws, size_t ws_size,
                              hipStream_t stream)
{
    const float* pred    = (const float*)d_in[0];
    const float* anchors = (const float*)d_in[1];
    float* out = (float*)d_out;

    int total = NBATCH * NBOX;
    int blocks = (total + 255) / 256;
    decode_kernel<<<blocks, 256, 0, stream>>>(pred, anchors, out);

    if (ws_size >= WS_NEEDED) {
        char* ws = (char*)d_ws;
        int*            nobj  = (int*)(ws + WS_NUMOBJ_OFF);
        unsigned short* order = (unsigned short*)(ws + WS_ORDER_OFF);
        float*          sobj  = (float*)(ws + WS_SOBJ_OFF);
        sort_kernel<<<NBATCH, 1024, 0, stream>>>(out, order, sobj, nobj);
        nms4_kernel<<<NBATCH, 1024, 0, stream>>>(out, order, sobj, nobj);
        epi_kernel<<<NBATCH, 256, 0, stream>>>(out, order, sobj, nobj);
    } else {
        nms_kernel<<<NBATCH, K2T, 0, stream>>>(out);
    }
}

// Round 10
// 174.084 us; speedup vs baseline: 1.8736x; 1.0482x over previous
//
#include <hip/hip_runtime.h>

#define NUMA 5
#define NCLS 80
#define AL 85          // 80 + 4 + 1
#define HW 361         // 19*19
#define NBOX 1805      // 5*361
#define NBATCH 128
#define NPAD 2048
#define K2T 256
#define MCAP 1024      // two-phase cap on num_obj (expected ~902 +/- 21)
#define NCHUNK 16      // MCAP / 64

// ---- d_ws layout (phase-split path) ----
#define WS_NUMOBJ_OFF 0                                  // int32 [128]
#define WS_ORDER_OFF  512                                // u16   [128][2048]
#define WS_SOBJ_OFF   (512 + NBATCH * NPAD * 2)          // f32   [128][2048]
#define WS_NEEDED     ((size_t)(WS_SOBJ_OFF + NBATCH * NPAD * 4))   // ~1.5 MB

// Exact-division-compare constant: MID = (0.45f + pred(0.45f))/2 exactly.
// RN32(inter/denom) >= 0.45f  <=>  inter >= denom*MID (real arithmetic)
//                            <=>  fma64(denom, MID, -inter) <= 0   (exact sign)
#define MID_CONST (30198987.0 / 67108864.0)

__device__ __forceinline__ unsigned long long bcast64(unsigned long long v, int t) {
    unsigned lo = (unsigned)__builtin_amdgcn_readlane((int)(unsigned)v, t);
    unsigned hi = (unsigned)__builtin_amdgcn_readlane((int)(unsigned)(v >> 32), t);
    return ((unsigned long long)hi << 32) | (unsigned long long)lo;
}

// ---------------------------------------------------------------------------
// Kernel 1: decode.  pred [B, 425, 19, 19] -> det [B, 1805, 7] written to out
// ---------------------------------------------------------------------------
__global__ __launch_bounds__(256) void decode_kernel(
    const float* __restrict__ pred,
    const float* __restrict__ anchors,
    float* __restrict__ det)
{
#pragma clang fp contract(off)
    int id = blockIdx.x * blockDim.x + threadIdx.x;
    if (id >= NBATCH * NBOX) return;
    int b = id / NBOX;
    int r = id - b * NBOX;
    int a = r / HW;
    int s = r - a * HW;
    int ci = s % 19;
    int cj = s / 19;

    const float* base = pred + ((size_t)(b * (NUMA * AL) + a * AL) * HW + s);
    float tx  = base[0 * HW];
    float ty  = base[1 * HW];
    float tw  = base[2 * HW];
    float th  = base[3 * HW];
    float obj = base[4 * HW];

    float cmax = base[5 * HW];
    int karg = 0;
#pragma unroll 4
    for (int k = 1; k < NCLS; ++k) {
        float c = base[(5 + k) * HW];
        if (c > cmax) { cmax = c; karg = k; }
    }

    float bx = (tx + (float)ci) / 19.0f;
    float by = (ty + (float)cj) / 19.0f;
    float aw = anchors[2 * a];
    float ah = anchors[2 * a + 1];
    float bw = expf(tw) * (aw / 19.0f);
    float bh = expf(th) * (ah / 19.0f);
    float prob = cmax * obj;
    float cid  = (float)karg;

    float* o = det + (size_t)(b * NBOX + r) * 7;
    o[0] = obj; o[1] = bx; o[2] = by; o[3] = bw; o[4] = bh; o[5] = cid; o[6] = prob;
}

// ---------------------------------------------------------------------------
// Kernel 2: per-image stable bitonic sort (desc by obj). 1024 threads/image.
// ---------------------------------------------------------------------------
__global__ __launch_bounds__(1024) void sort_kernel(
    const float* __restrict__ det,
    unsigned short* __restrict__ order_g,
    float* __restrict__ sobj_g,
    int* __restrict__ nobj_g)
{
    __shared__ unsigned long long keys[NPAD];
    __shared__ int cnt_sh;
    const int b = blockIdx.x;
    const int tid = threadIdx.x;
    const float* detb = det + (size_t)b * NBOX * 7;

    for (int n = tid; n < NPAD; n += 1024) {
        keys[n] = (n < NBOX)
            ? (((unsigned long long)__float_as_uint(detb[n * 7]) << 32)
               | (unsigned long long)(2047 - n))
            : 0ull;
    }
    if (tid == 0) cnt_sh = 0;
    __syncthreads();

    for (unsigned k = 2; k <= NPAD; k <<= 1) {
        for (unsigned j = k >> 1; j > 0; j >>= 1) {
            for (unsigned idx = tid; idx < NPAD; idx += 1024) {
                unsigned ixj = idx ^ j;
                if (ixj > idx) {
                    unsigned long long av = keys[idx], bv = keys[ixj];
                    bool up = ((idx & k) == 0);
                    if (up ? (av < bv) : (av > bv)) { keys[idx] = bv; keys[ixj] = av; }
                }
            }
            __syncthreads();
        }
    }

    int cnt = 0;
    for (int r = tid; r < NBOX; r += 1024) {
        unsigned long long kk = keys[r];
        order_g[b * NPAD + r] = (unsigned short)(2047u - (unsigned)(kk & 0xffffffffu));
        float ob = __uint_as_float((unsigned)(kk >> 32));
        sobj_g[b * NPAD + r] = ob;
        cnt += (ob > 0.5f) ? 1 : 0;
    }
    atomicAdd(&cnt_sh, cnt);
    __syncthreads();
    if (tid == 0) nobj_g[b] = cnt_sh;
}

// ---------------------------------------------------------------------------
// Kernel 3: two-phase NMS, one block (1024 thr, 156 KB LDS) per image.
// Phase 1 (16 waves): SUP[cc][r] = bit-column of chunk-cc boxes suppressing
//   box r; diagonal tiles ALSO capture bit-ROWS (DROW[c][t] = same-chunk
//   boxes suppressed by t) via per-t ballot.
// Phase 2 (wave 0): within-chunk greedy scan over ROWS held in lane regs,
//   broadcast by v_readlane (~25 cyc/step, no ballots); cross-chunk apply
//   stays lane-parallel over columns.
// ---------------------------------------------------------------------------
__global__ __launch_bounds__(1024, 1) void nms4_kernel(
    const float* __restrict__ det,
    const unsigned short* __restrict__ order_g,
    float* __restrict__ sobj_g,
    const int* __restrict__ nobj_g)
{
#pragma clang fp contract(off)
    __shared__ float4 QS[MCAP];                          // 16 KB
    __shared__ float  AS[MCAP];                          // 4 KB
    __shared__ unsigned long long SUP[NCHUNK][MCAP];     // 128 KB
    __shared__ unsigned long long DROW[NCHUNK][64];      // 8 KB
    const int b = blockIdx.x;
    const int tid = threadIdx.x;
    const int lane = tid & 63;
    const int wv = tid >> 6;
    const float* detb = det + (size_t)b * NBOX * 7;
    const unsigned short* ord = order_g + b * NPAD;
    float* sobj = sobj_g + b * NPAD;
    const int num_obj = nobj_g[b];
    const int M = (num_obj < MCAP) ? num_obj : MCAP;

    if (num_obj <= MCAP) {
        // --- stage sorted boxes ---
        {
            const float* row = detb + (int)ord[tid] * 7;
            float bx = row[1], by = row[2], bw = row[3], bh = row[4];
            QS[tid] = make_float4(bx - 0.5f * bw, by - 0.5f * bh,
                                  bx + 0.5f * bw, by + 0.5f * bh);
            AS[tid] = bw * bh;
        }
        __syncthreads();

        // --- phase 1: build suppression columns (+ diagonal rows) ---
        for (int k = wv; k < 136; k += 16) {
            int c2 = 0;
            while ((c2 + 1) * (c2 + 2) / 2 <= k) ++c2;   // tile -> (c2, cc)
            int cc = k - c2 * (c2 + 1) / 2;
            if (c2 * 64 < M) {
                int j = c2 * 64 + lane;
                float4 qj = QS[j];
                float  aj = AS[j];
                unsigned long long w = 0ull;
                if (cc == c2) {
                    unsigned long long myrow = 0ull;
                    for (int t = 0; t < 64; ++t) {
                        int it = cc * 64 + t;
                        float4 qt = QS[it];
                        float  at = AS[it];
                        float iw = fmaxf(fminf(qj.z, qt.z) - fmaxf(qj.x, qt.x), 0.0f);
                        float ih = fmaxf(fminf(qj.w, qt.w) - fmaxf(qj.y, qt.y), 0.0f);
                        float inter = iw * ih;
                        float denom = (aj + at) - inter;
                        bool supp = (fma((double)denom, MID_CONST,
                                         -(double)inter) <= 0.0)
                                    && (t < lane);
                        unsigned long long bb = __ballot(supp);
                        w |= supp ? (1ull << t) : 0ull;
                        if (lane == t) myrow = bb;
                    }
                    DROW[cc][lane] = myrow;
                } else {
#pragma unroll 8
                    for (int t = 0; t < 64; ++t) {
                        int it = cc * 64 + t;
                        float4 qt = QS[it];
                        float  at = AS[it];
                        float iw = fmaxf(fminf(qj.z, qt.z) - fmaxf(qj.x, qt.x), 0.0f);
                        float ih = fmaxf(fminf(qj.w, qt.w) - fmaxf(qj.y, qt.y), 0.0f);
                        float inter = iw * ih;
                        float denom = (aj + at) - inter;
                        bool supp = (fma((double)denom, MID_CONST,
                                         -(double)inter) <= 0.0);
                        w |= supp ? (1ull << t) : 0ull;
                    }
                }
                SUP[cc][j] = w;
            }
        }
        __syncthreads();

        // --- phase 2: serial greedy scan (wave 0, row-register based) ---
        if (wv == 0) {
            unsigned rm = 0u;                  // bit c = my box in chunk c dead
            for (int c = 0; c < NCHUNK && c * 64 < M; ++c) {
                int rem_in = M - c * 64;
                unsigned long long cmask =
                    (rem_in >= 64) ? ~0ull : ((1ull << rem_in) - 1ull);
                unsigned long long deadw = __ballot((rm >> c) & 1u);
                unsigned long long rowreg = DROW[c][lane];
                unsigned long long rem = cmask & ~deadw;
                const unsigned long long rem0 = rem;
                unsigned long long S = 0ull;   // survivors of chunk c
                while (rem) {
                    int t = (int)__builtin_ctzll(rem);
                    S |= (1ull << t);
                    unsigned long long row_t = bcast64(rowreg, t);
                    rem &= ~row_t;
                    rem &= ~(1ull << t);
                }
                // newly dead within chunk c (candidate but not survivor)
                unsigned long long deadnew = rem0 & ~S;
                rm |= (unsigned)((deadnew >> lane) & 1ull) << c;
                // cross-chunk apply (lane-parallel over columns)
                for (int c2 = c + 1; c2 < NCHUNK && c2 * 64 < M; ++c2) {
                    unsigned long long w2 = SUP[c][c2 * 64 + lane];
                    rm |= ((w2 & S) != 0ull) ? (1u << c2) : 0u;
                }
            }
            for (int c2 = 0; c2 < NCHUNK; ++c2) {
                int j = c2 * 64 + lane;
                if (j < M && ((rm >> c2) & 1u)) sobj[j] = 0.0f;
            }
        }
    } else {
        // fallback (num_obj > 1024; statistically unreachable): serial greedy
        for (int i = 0; i < num_obj; ++i) {
            if (sobj[i] > 0.01f) {
                const float* ri = detb + (int)ord[i] * 7;
                float bxi = ri[1], byi = ri[2], bwi = ri[3], bhi = ri[4];
                float xi1 = bxi - 0.5f * bwi, xi2 = bxi + 0.5f * bwi;
                float yi1 = byi - 0.5f * bhi, yi2 = byi + 0.5f * bhi;
                float ai = bwi * bhi;
                for (int j = i + 1 + tid; j < num_obj; j += 1024) {
                    const float* rj = detb + (int)ord[j] * 7;
                    float bxj = rj[1], byj = rj[2], bwj = rj[3], bhj = rj[4];
                    float x1j = bxj - 0.5f * bwj, x2j = bxj + 0.5f * bwj;
                    float y1j = byj - 0.5f * bhj, y2j = byj + 0.5f * bhj;
                    float aj = bwj * bhj;
                    float iw = fmaxf(fminf(x2j, xi2) - fmaxf(x1j, xi1), 0.0f);
                    float ih = fmaxf(fminf(y2j, yi2) - fmaxf(y1j, yi1), 0.0f);
                    float inter = iw * ih;
                    float iou = inter / ((aj + ai) - inter);
                    if (iou >= 0.45f) sobj[j] = 0.0f;
                }
            }
            __syncthreads();
        }
    }
}

// ---------------------------------------------------------------------------
// Kernel 4: epilogue. Gather rows in sorted order, apply filters, write det
// in place (all reads before barrier, all writes after).
// ---------------------------------------------------------------------------
__global__ __launch_bounds__(256) void epi_kernel(
    float* __restrict__ det,
    const unsigned short* __restrict__ order_g,
    const float* __restrict__ sobj_g,
    const int* __restrict__ nobj_g)
{
#pragma clang fp contract(off)
    const int b = blockIdx.x;
    const int tid = threadIdx.x;
    float* detb = det + (size_t)b * NBOX * 7;
    const unsigned short* ord = order_g + b * NPAD;
    const float* sobj = sobj_g + b * NPAD;
    const int num_obj = nobj_g[b];

    float v0[8], v1[8], v2[8], v3[8], v4[8], v5[8], v6[8], msk[8];
#pragma unroll
    for (int c = 0; c < 8; ++c) {
        int r = tid + c * 256;
        if (r < NBOX) {
            const float* row = detb + (int)ord[r] * 7;
            float obj = row[0], bx = row[1], by = row[2], bw = row[3];
            float bh = row[4], cid = row[5], prob = row[6];
            bool keep = (r < num_obj) && (sobj[r] > 0.01f) && (r != num_obj - 1);
            float p = prob * ((prob > 0.1f) ? 1.0f : 0.0f);
            bool fin = keep && (p > 0.01f) && (bw * bw > 0.0004f);
            v0[c] = obj; v1[c] = bx; v2[c] = by; v3[c] = bw; v4[c] = bh;
            v5[c] = cid; v6[c] = p;
            msk[c] = fin ? 1.0f : 0.0f;
        }
    }
    __syncthreads();
#pragma unroll
    for (int c = 0; c < 8; ++c) {
        int r = tid + c * 256;
        if (r < NBOX) {
            float* o = detb + r * 7;
            o[0] = v0[c] * msk[c];
            o[1] = v1[c] * msk[c];
            o[2] = v2[c] * msk[c];
            o[3] = v3[c] * msk[c];
            o[4] = v4[c] * msk[c];
            o[5] = v5[c] * msk[c];
            o[6] = v6[c] * msk[c];
        }
    }
}

// ---------------------------------------------------------------------------
// Fallback monolithic kernel (used only if ws_size < WS_NEEDED).
// ---------------------------------------------------------------------------
__global__ __launch_bounds__(K2T, 1) void nms_kernel(float* __restrict__ det)
{
#pragma clang fp contract(off)
    __shared__ alignas(16) union {
        unsigned long long keys[NPAD];
        struct { float4 q[MCAP]; float area[MCAP]; } box;
    } U;
    __shared__ float s_obj[NBOX];
    __shared__ unsigned short order[NBOX];
    __shared__ int num_obj_sh;

    const int b = blockIdx.x;
    const int tid = threadIdx.x;
    float* detb = det + (size_t)b * NBOX * 7;

    for (int n = tid; n < NPAD; n += K2T) {
        if (n < NBOX) {
            unsigned ob = __float_as_uint(detb[n * 7 + 0]);
            U.keys[n] = ((unsigned long long)ob << 32) | (unsigned long long)(2047 - n);
        } else U.keys[n] = 0ull;
    }
    if (tid == 0) num_obj_sh = 0;
    __syncthreads();

    for (unsigned k = 2; k <= NPAD; k <<= 1) {
        for (unsigned j = k >> 1; j > 0; j >>= 1) {
            for (unsigned idx = tid; idx < NPAD; idx += K2T) {
                unsigned ixj = idx ^ j;
                if (ixj > idx) {
                    unsigned long long av = U.keys[idx], bv = U.keys[ixj];
                    bool up = ((idx & k) == 0);
                    if (up ? (av < bv) : (av > bv)) { U.keys[idx] = bv; U.keys[ixj] = av; }
                }
            }
            __syncthreads();
        }
    }

    int cnt = 0;
    for (int r = tid; r < NBOX; r += K2T) {
        unsigned long long kk = U.keys[r];
        order[r] = (unsigned short)(2047u - (unsigned)(kk & 0xffffffffu));
        float ob = __uint_as_float((unsigned)(kk >> 32));
        s_obj[r] = ob;
        cnt += (ob > 0.5f) ? 1 : 0;
    }
    atomicAdd(&num_obj_sh, cnt);
    __syncthreads();
    const int num_obj = num_obj_sh;

    for (int i = 0; i < num_obj; ++i) {
        if (s_obj[i] > 0.01f) {
            const float* ri = detb + (int)order[i] * 7;
            float bxi = ri[1], byi = ri[2], bwi = ri[3], bhi = ri[4];
            float xi1 = bxi - 0.5f * bwi, xi2 = bxi + 0.5f * bwi;
            float yi1 = byi - 0.5f * bhi, yi2 = byi + 0.5f * bhi;
            float ai = bwi * bhi;
            for (int j = i + 1 + tid; j < num_obj; j += K2T) {
                const float* rj = detb + (int)order[j] * 7;
                float bxj = rj[1], byj = rj[2], bwj = rj[3], bhj = rj[4];
                float x1j = bxj - 0.5f * bwj, x2j = bxj + 0.5f * bwj;
                float y1j = byj - 0.5f * bhj, y2j = byj + 0.5f * bhj;
                float aj = bwj * bhj;
                float iw = fmaxf(fminf(x2j, xi2) - fmaxf(x1j, xi1), 0.0f);
                float ih = fmaxf(fminf(y2j, yi2) - fmaxf(y1j, yi1), 0.0f);
                float inter = iw * ih;
                float iou = inter / ((aj + ai) - inter);
                if (iou >= 0.45f) s_obj[j] = 0.0f;
            }
        }
        __syncthreads();
    }

    float v0[8], v1[8], v2[8], v3[8], v4[8], v5[8], v6[8], msk[8];
#pragma unroll
    for (int c = 0; c < 8; ++c) {
        int r = tid + c * K2T;
        if (r < NBOX) {
            const float* row = detb + (int)order[r] * 7;
            float obj = row[0], bx = row[1], by = row[2], bw = row[3];
            float bh = row[4], cid = row[5], prob = row[6];
            bool keep = (r < num_obj) && (s_obj[r] > 0.01f) && (r != num_obj - 1);
            float p = prob * ((prob > 0.1f) ? 1.0f : 0.0f);
            bool fin = keep && (p > 0.01f) && (bw * bw > 0.0004f);
            v0[c] = obj; v1[c] = bx; v2[c] = by; v3[c] = bw; v4[c] = bh;
            v5[c] = cid; v6[c] = p;
            msk[c] = fin ? 1.0f : 0.0f;
        }
    }
    __syncthreads();
#pragma unroll
    for (int c = 0; c < 8; ++c) {
        int r = tid + c * K2T;
        if (r < NBOX) {
            float* o = detb + r * 7;
            o[0] = v0[c] * msk[c]; o[1] = v1[c] * msk[c]; o[2] = v2[c] * msk[c];
            o[3] = v3[c] * msk[c]; o[4] = v4[c] * msk[c]; o[5] = v5[c] * msk[c];
            o[6] = v6[c] * msk[c];
        }
    }
}

extern "C" void kernel_launch(void* const* d_in, const int* in_sizes, int n_in,
                              void* d_out, int out_size, void* d_ws, size_t ws_size,
                              hipStream_t stream)
{
    const float* pred    = (const float*)d_in[0];
    const float* anchors = (const float*)d_in[1];
    float* out = (float*)d_out;

    int total = NBATCH * NBOX;
    int blocks = (total + 255) / 256;
    decode_kernel<<<blocks, 256, 0, stream>>>(pred, anchors, out);

    if (ws_size >= WS_NEEDED) {
        char* ws = (char*)d_ws;
        int*            nobj  = (int*)(ws + WS_NUMOBJ_OFF);
        unsigned short* order = (unsigned short*)(ws + WS_ORDER_OFF);
        float*          sobj  = (float*)(ws + WS_SOBJ_OFF);
        sort_kernel<<<NBATCH, 1024, 0, stream>>>(out, order, sobj, nobj);
        nms4_kernel<<<NBATCH, 1024, 0, stream>>>(out, order, sobj, nobj);
        epi_kernel<<<NBATCH, 256, 0, stream>>>(out, order, sobj, nobj);
    } else {
        nms_kernel<<<NBATCH, K2T, 0, stream>>>(out);
    }
}

// Round 11
// 162.019 us; speedup vs baseline: 2.0131x; 1.0745x over previous
//
#include <hip/hip_runtime.h>

#define NUMA 5
#define NCLS 80
#define AL 85          // 80 + 4 + 1
#define HW 361         // 19*19
#define NBOX 1805      // 5*361
#define NBATCH 128
#define NPAD 2048
#define K2T 256
#define MCAP 1024      // two-phase cap on num_obj (expected ~902 +/- 21)
#define NCHUNK 16      // MCAP / 64
#define NSPLIT 4       // phase-1 blocks per image

// ---- d_ws layout ----
#define WS_NUMOBJ_OFF 0                                  // int32 [128]
#define WS_ORDER_OFF  512                                // u16   [128][2048]
#define WS_SOBJ_OFF   (512 + NBATCH * NPAD * 2)          // f32   [128][2048]
#define WS_NEEDED     ((size_t)(WS_SOBJ_OFF + NBATCH * NPAD * 4))   // ~1.5 MB
#define WS_SUP_OFF    WS_NEEDED                          // u64 [128][16][1024]
#define WS_DROW_OFF   (WS_SUP_OFF + (size_t)NBATCH * NCHUNK * MCAP * 8)
#define WS_NEEDED2    (WS_DROW_OFF + (size_t)NBATCH * NCHUNK * 64 * 8)  // ~19.4 MB

// Exact-division-compare constant: MID = (0.45f + pred(0.45f))/2 exactly.
// RN32(inter/denom) >= 0.45f  <=>  fma64(denom, MID, -inter) <= 0 (exact sign)
#define MID_CONST (30198987.0 / 67108864.0)

__device__ __forceinline__ unsigned long long bcast64(unsigned long long v, int t) {
    unsigned lo = (unsigned)__builtin_amdgcn_readlane((int)(unsigned)v, t);
    unsigned hi = (unsigned)__builtin_amdgcn_readlane((int)(unsigned)(v >> 32), t);
    return ((unsigned long long)hi << 32) | (unsigned long long)lo;
}

// ---------------------------------------------------------------------------
// Kernel 1: decode.  pred [B, 425, 19, 19] -> det [B, 1805, 7] written to out
// ---------------------------------------------------------------------------
__global__ __launch_bounds__(256) void decode_kernel(
    const float* __restrict__ pred,
    const float* __restrict__ anchors,
    float* __restrict__ det)
{
#pragma clang fp contract(off)
    int id = blockIdx.x * blockDim.x + threadIdx.x;
    if (id >= NBATCH * NBOX) return;
    int b = id / NBOX;
    int r = id - b * NBOX;
    int a = r / HW;
    int s = r - a * HW;
    int ci = s % 19;
    int cj = s / 19;

    const float* base = pred + ((size_t)(b * (NUMA * AL) + a * AL) * HW + s);
    float tx  = base[0 * HW];
    float ty  = base[1 * HW];
    float tw  = base[2 * HW];
    float th  = base[3 * HW];
    float obj = base[4 * HW];

    float cmax = base[5 * HW];
    int karg = 0;
#pragma unroll 4
    for (int k = 1; k < NCLS; ++k) {
        float c = base[(5 + k) * HW];
        if (c > cmax) { cmax = c; karg = k; }
    }

    float bx = (tx + (float)ci) / 19.0f;
    float by = (ty + (float)cj) / 19.0f;
    float aw = anchors[2 * a];
    float ah = anchors[2 * a + 1];
    float bw = expf(tw) * (aw / 19.0f);
    float bh = expf(th) * (ah / 19.0f);
    float prob = cmax * obj;
    float cid  = (float)karg;

    float* o = det + (size_t)(b * NBOX + r) * 7;
    o[0] = obj; o[1] = bx; o[2] = by; o[3] = bw; o[4] = bh; o[5] = cid; o[6] = prob;
}

// ---------------------------------------------------------------------------
// Kernel 2: per-image stable bitonic sort (desc by obj). 1024 threads/image.
// ---------------------------------------------------------------------------
__global__ __launch_bounds__(1024) void sort_kernel(
    const float* __restrict__ det,
    unsigned short* __restrict__ order_g,
    float* __restrict__ sobj_g,
    int* __restrict__ nobj_g)
{
    __shared__ unsigned long long keys[NPAD];
    __shared__ int cnt_sh;
    const int b = blockIdx.x;
    const int tid = threadIdx.x;
    const float* detb = det + (size_t)b * NBOX * 7;

    for (int n = tid; n < NPAD; n += 1024) {
        keys[n] = (n < NBOX)
            ? (((unsigned long long)__float_as_uint(detb[n * 7]) << 32)
               | (unsigned long long)(2047 - n))
            : 0ull;
    }
    if (tid == 0) cnt_sh = 0;
    __syncthreads();

    for (unsigned k = 2; k <= NPAD; k <<= 1) {
        for (unsigned j = k >> 1; j > 0; j >>= 1) {
            for (unsigned idx = tid; idx < NPAD; idx += 1024) {
                unsigned ixj = idx ^ j;
                if (ixj > idx) {
                    unsigned long long av = keys[idx], bv = keys[ixj];
                    bool up = ((idx & k) == 0);
                    if (up ? (av < bv) : (av > bv)) { keys[idx] = bv; keys[ixj] = av; }
                }
            }
            __syncthreads();
        }
    }

    int cnt = 0;
    for (int r = tid; r < NBOX; r += 1024) {
        unsigned long long kk = keys[r];
        order_g[b * NPAD + r] = (unsigned short)(2047u - (unsigned)(kk & 0xffffffffu));
        float ob = __uint_as_float((unsigned)(kk >> 32));
        sobj_g[b * NPAD + r] = ob;
        cnt += (ob > 0.5f) ? 1 : 0;
    }
    atomicAdd(&cnt_sh, cnt);
    __syncthreads();
    if (tid == 0) nobj_g[b] = cnt_sh;
}

// ---------------------------------------------------------------------------
// Kernel 3a: suppression-matrix build. Grid = 128 * NSPLIT blocks (2/CU, full
// occupancy). Each block: stage boxes in 20 KB LDS, compute its share of the
// 136 chunk-pair tiles, write SUP columns (+ diagonal DROW) to d_ws.
// ---------------------------------------------------------------------------
__global__ __launch_bounds__(1024) void sup_kernel(
    const float* __restrict__ det,
    const unsigned short* __restrict__ order_g,
    const int* __restrict__ nobj_g,
    unsigned long long* __restrict__ sup_g,
    unsigned long long* __restrict__ drow_g)
{
#pragma clang fp contract(off)
    __shared__ float4 QS[MCAP];                          // 16 KB
    __shared__ float  AS[MCAP];                          // 4 KB
    const int bb = blockIdx.x;
    const int b = bb / NSPLIT;
    const int part = bb - b * NSPLIT;
    const int tid = threadIdx.x;
    const int lane = tid & 63;
    const int wv = tid >> 6;
    const int num_obj = nobj_g[b];
    if (num_obj > MCAP) return;                          // scanepi fallback handles
    const int M = num_obj;
    const float* detb = det + (size_t)b * NBOX * 7;
    const unsigned short* ord = order_g + b * NPAD;

    {
        const float* row = detb + (int)ord[tid] * 7;
        float bx = row[1], by = row[2], bw = row[3], bh = row[4];
        QS[tid] = make_float4(bx - 0.5f * bw, by - 0.5f * bh,
                              bx + 0.5f * bw, by + 0.5f * bh);
        AS[tid] = bw * bh;
    }
    __syncthreads();

    for (int k = part * 16 + wv; k < 136; k += 16 * NSPLIT) {
        int c2 = 0;
        while ((c2 + 1) * (c2 + 2) / 2 <= k) ++c2;       // tile -> (c2, cc<=c2)
        int cc = k - c2 * (c2 + 1) / 2;
        if (c2 * 64 < M) {
            int j = c2 * 64 + lane;
            float4 qj = QS[j];
            float  aj = AS[j];
            unsigned long long w = 0ull;
            if (cc == c2) {
                unsigned long long myrow = 0ull;
                for (int t = 0; t < 64; ++t) {
                    float4 qt = QS[cc * 64 + t];
                    float  at = AS[cc * 64 + t];
                    float iw = fmaxf(fminf(qj.z, qt.z) - fmaxf(qj.x, qt.x), 0.0f);
                    float ih = fmaxf(fminf(qj.w, qt.w) - fmaxf(qj.y, qt.y), 0.0f);
                    float inter = iw * ih;
                    float denom = (aj + at) - inter;
                    bool supp = (fma((double)denom, MID_CONST,
                                     -(double)inter) <= 0.0) && (t < lane);
                    unsigned long long bb2 = __ballot(supp);
                    w |= supp ? (1ull << t) : 0ull;
                    if (lane == t) myrow = bb2;
                }
                drow_g[((size_t)b * NCHUNK + cc) * 64 + lane] = myrow;
            } else {
#pragma unroll 8
                for (int t = 0; t < 64; ++t) {
                    float4 qt = QS[cc * 64 + t];
                    float  at = AS[cc * 64 + t];
                    float iw = fmaxf(fminf(qj.z, qt.z) - fmaxf(qj.x, qt.x), 0.0f);
                    float ih = fmaxf(fminf(qj.w, qt.w) - fmaxf(qj.y, qt.y), 0.0f);
                    float inter = iw * ih;
                    float denom = (aj + at) - inter;
                    bool supp = (fma((double)denom, MID_CONST,
                                     -(double)inter) <= 0.0);
                    w |= supp ? (1ull << t) : 0ull;
                }
            }
            sup_g[((size_t)b * NCHUNK + cc) * MCAP + j] = w;
        }
    }
}

// ---------------------------------------------------------------------------
// Kernel 3b: greedy scan (wave 0, register-rows) + epilogue, fused.
// 256 threads per image. sobj staged in LDS; DROW staged in LDS.
// ---------------------------------------------------------------------------
__global__ __launch_bounds__(256) void scanepi_kernel(
    float* __restrict__ det,
    const unsigned short* __restrict__ order_g,
    const float* __restrict__ sobj_g,
    const int* __restrict__ nobj_g,
    const unsigned long long* __restrict__ sup_g,
    const unsigned long long* __restrict__ drow_g)
{
#pragma clang fp contract(off)
    __shared__ float sobj_l[NPAD];                       // 8 KB
    __shared__ unsigned long long DR[NCHUNK][64];        // 8 KB
    const int b = blockIdx.x;
    const int tid = threadIdx.x;
    const int lane = tid & 63;
    float* detb = det + (size_t)b * NBOX * 7;
    const unsigned short* ord = order_g + b * NPAD;
    const int num_obj = nobj_g[b];
    const int M = (num_obj < MCAP) ? num_obj : MCAP;

    // stage sobj + DROW
#pragma unroll
    for (int c = 0; c < 8; ++c) sobj_l[tid + c * 256] = sobj_g[b * NPAD + tid + c * 256];
    if (num_obj <= MCAP) {
#pragma unroll
        for (int c = 0; c < 4; ++c) {
            int i = tid + c * 256;   // 1024 words
            ((unsigned long long*)DR)[i] = drow_g[(size_t)b * NCHUNK * 64 + i];
        }
    }
    __syncthreads();

    if (num_obj <= MCAP) {
        if (tid < 64) {
            unsigned rm = 0u;                  // bit c = my box in chunk c dead
            for (int c = 0; c < NCHUNK && c * 64 < M; ++c) {
                int rem_in = M - c * 64;
                unsigned long long cmask =
                    (rem_in >= 64) ? ~0ull : ((1ull << rem_in) - 1ull);
                unsigned long long deadw = __ballot((rm >> c) & 1u);
                unsigned long long rowreg = DR[c][lane];
                unsigned long long rem = cmask & ~deadw;
                const unsigned long long rem0 = rem;
                unsigned long long S = 0ull;   // survivors of chunk c
                while (rem) {
                    int t = (int)__builtin_ctzll(rem);
                    S |= (1ull << t);
                    unsigned long long row_t = bcast64(rowreg, t);
                    rem &= ~row_t;
                    rem &= ~(1ull << t);
                }
                unsigned long long deadnew = rem0 & ~S;
                rm |= (unsigned)((deadnew >> lane) & 1ull) << c;
                const unsigned long long* supc =
                    sup_g + ((size_t)b * NCHUNK + c) * MCAP;
                for (int c2 = c + 1; c2 < NCHUNK && c2 * 64 < M; ++c2) {
                    unsigned long long w2 = supc[c2 * 64 + lane];
                    rm |= ((w2 & S) != 0ull) ? (1u << c2) : 0u;
                }
            }
#pragma unroll
            for (int c2 = 0; c2 < NCHUNK; ++c2) {
                int j = c2 * 64 + lane;
                if (j < M && ((rm >> c2) & 1u)) sobj_l[j] = 0.0f;
            }
        }
        __syncthreads();
    } else {
        // fallback (num_obj > 1024; statistically unreachable): serial greedy
        for (int i = 0; i < num_obj; ++i) {
            if (sobj_l[i] > 0.01f) {
                const float* ri = detb + (int)ord[i] * 7;
                float bxi = ri[1], byi = ri[2], bwi = ri[3], bhi = ri[4];
                float xi1 = bxi - 0.5f * bwi, xi2 = bxi + 0.5f * bwi;
                float yi1 = byi - 0.5f * bhi, yi2 = byi + 0.5f * bhi;
                float ai = bwi * bhi;
                for (int j = i + 1 + tid; j < num_obj; j += 256) {
                    const float* rj = detb + (int)ord[j] * 7;
                    float bxj = rj[1], byj = rj[2], bwj = rj[3], bhj = rj[4];
                    float x1j = bxj - 0.5f * bwj, x2j = bxj + 0.5f * bwj;
                    float y1j = byj - 0.5f * bhj, y2j = byj + 0.5f * bhj;
                    float aj = bwj * bhj;
                    float iw = fmaxf(fminf(x2j, xi2) - fmaxf(x1j, xi1), 0.0f);
                    float ih = fmaxf(fminf(y2j, yi2) - fmaxf(y1j, yi1), 0.0f);
                    float inter = iw * ih;
                    float iou = inter / ((aj + ai) - inter);
                    if (iou >= 0.45f) sobj_l[j] = 0.0f;
                }
            }
            __syncthreads();
        }
    }

    // --- epilogue: read rows in sorted order, filter, write in place ---
    float v0[8], v1[8], v2[8], v3[8], v4[8], v5[8], v6[8], msk[8];
#pragma unroll
    for (int c = 0; c < 8; ++c) {
        int r = tid + c * 256;
        if (r < NBOX) {
            const float* row = detb + (int)ord[r] * 7;
            float obj = row[0], bx = row[1], by = row[2], bw = row[3];
            float bh = row[4], cid = row[5], prob = row[6];
            bool keep = (r < num_obj) && (sobj_l[r] > 0.01f) && (r != num_obj - 1);
            float p = prob * ((prob > 0.1f) ? 1.0f : 0.0f);
            bool fin = keep && (p > 0.01f) && (bw * bw > 0.0004f);
            v0[c] = obj; v1[c] = bx; v2[c] = by; v3[c] = bw; v4[c] = bh;
            v5[c] = cid; v6[c] = p;
            msk[c] = fin ? 1.0f : 0.0f;
        }
    }
    __syncthreads();
#pragma unroll
    for (int c = 0; c < 8; ++c) {
        int r = tid + c * 256;
        if (r < NBOX) {
            float* o = detb + r * 7;
            o[0] = v0[c] * msk[c];
            o[1] = v1[c] * msk[c];
            o[2] = v2[c] * msk[c];
            o[3] = v3[c] * msk[c];
            o[4] = v4[c] * msk[c];
            o[5] = v5[c] * msk[c];
            o[6] = v6[c] * msk[c];
        }
    }
}

// ---------------------------------------------------------------------------
// Middle fallback (1.5MB <= ws < 19.4MB): round-10 monolithic two-phase NMS.
// ---------------------------------------------------------------------------
__global__ __launch_bounds__(1024, 1) void nms4_kernel(
    const float* __restrict__ det,
    const unsigned short* __restrict__ order_g,
    float* __restrict__ sobj_g,
    const int* __restrict__ nobj_g)
{
#pragma clang fp contract(off)
    __shared__ float4 QS[MCAP];
    __shared__ float  AS[MCAP];
    __shared__ unsigned long long SUP[NCHUNK][MCAP];
    __shared__ unsigned long long DROW[NCHUNK][64];
    const int b = blockIdx.x;
    const int tid = threadIdx.x;
    const int lane = tid & 63;
    const int wv = tid >> 6;
    const float* detb = det + (size_t)b * NBOX * 7;
    const unsigned short* ord = order_g + b * NPAD;
    float* sobj = sobj_g + b * NPAD;
    const int num_obj = nobj_g[b];
    const int M = (num_obj < MCAP) ? num_obj : MCAP;

    if (num_obj <= MCAP) {
        {
            const float* row = detb + (int)ord[tid] * 7;
            float bx = row[1], by = row[2], bw = row[3], bh = row[4];
            QS[tid] = make_float4(bx - 0.5f * bw, by - 0.5f * bh,
                                  bx + 0.5f * bw, by + 0.5f * bh);
            AS[tid] = bw * bh;
        }
        __syncthreads();

        for (int k = wv; k < 136; k += 16) {
            int c2 = 0;
            while ((c2 + 1) * (c2 + 2) / 2 <= k) ++c2;
            int cc = k - c2 * (c2 + 1) / 2;
            if (c2 * 64 < M) {
                int j = c2 * 64 + lane;
                float4 qj = QS[j];
                float  aj = AS[j];
                unsigned long long w = 0ull;
                if (cc == c2) {
                    unsigned long long myrow = 0ull;
                    for (int t = 0; t < 64; ++t) {
                        float4 qt = QS[cc * 64 + t];
                        float  at = AS[cc * 64 + t];
                        float iw = fmaxf(fminf(qj.z, qt.z) - fmaxf(qj.x, qt.x), 0.0f);
                        float ih = fmaxf(fminf(qj.w, qt.w) - fmaxf(qj.y, qt.y), 0.0f);
                        float inter = iw * ih;
                        float denom = (aj + at) - inter;
                        bool supp = (fma((double)denom, MID_CONST,
                                         -(double)inter) <= 0.0) && (t < lane);
                        unsigned long long bb = __ballot(supp);
                        w |= supp ? (1ull << t) : 0ull;
                        if (lane == t) myrow = bb;
                    }
                    DROW[cc][lane] = myrow;
                } else {
#pragma unroll 8
                    for (int t = 0; t < 64; ++t) {
                        float4 qt = QS[cc * 64 + t];
                        float  at = AS[cc * 64 + t];
                        float iw = fmaxf(fminf(qj.z, qt.z) - fmaxf(qj.x, qt.x), 0.0f);
                        float ih = fmaxf(fminf(qj.w, qt.w) - fmaxf(qj.y, qt.y), 0.0f);
                        float inter = iw * ih;
                        float denom = (aj + at) - inter;
                        bool supp = (fma((double)denom, MID_CONST,
                                         -(double)inter) <= 0.0);
                        w |= supp ? (1ull << t) : 0ull;
                    }
                }
                SUP[cc][j] = w;
            }
        }
        __syncthreads();

        if (wv == 0) {
            unsigned rm = 0u;
            for (int c = 0; c < NCHUNK && c * 64 < M; ++c) {
                int rem_in = M - c * 64;
                unsigned long long cmask =
                    (rem_in >= 64) ? ~0ull : ((1ull << rem_in) - 1ull);
                unsigned long long deadw = __ballot((rm >> c) & 1u);
                unsigned long long rowreg = DROW[c][lane];
                unsigned long long rem = cmask & ~deadw;
                const unsigned long long rem0 = rem;
                unsigned long long S = 0ull;
                while (rem) {
                    int t = (int)__builtin_ctzll(rem);
                    S |= (1ull << t);
                    unsigned long long row_t = bcast64(rowreg, t);
                    rem &= ~row_t;
                    rem &= ~(1ull << t);
                }
                unsigned long long deadnew = rem0 & ~S;
                rm |= (unsigned)((deadnew >> lane) & 1ull) << c;
                for (int c2 = c + 1; c2 < NCHUNK && c2 * 64 < M; ++c2) {
                    unsigned long long w2 = SUP[c][c2 * 64 + lane];
                    rm |= ((w2 & S) != 0ull) ? (1u << c2) : 0u;
                }
            }
            for (int c2 = 0; c2 < NCHUNK; ++c2) {
                int j = c2 * 64 + lane;
                if (j < M && ((rm >> c2) & 1u)) sobj[j] = 0.0f;
            }
        }
    } else {
        for (int i = 0; i < num_obj; ++i) {
            if (sobj[i] > 0.01f) {
                const float* ri = detb + (int)ord[i] * 7;
                float bxi = ri[1], byi = ri[2], bwi = ri[3], bhi = ri[4];
                float xi1 = bxi - 0.5f * bwi, xi2 = bxi + 0.5f * bwi;
                float yi1 = byi - 0.5f * bhi, yi2 = byi + 0.5f * bhi;
                float ai = bwi * bhi;
                for (int j = i + 1 + tid; j < num_obj; j += 1024) {
                    const float* rj = detb + (int)ord[j] * 7;
                    float bxj = rj[1], byj = rj[2], bwj = rj[3], bhj = rj[4];
                    float x1j = bxj - 0.5f * bwj, x2j = bxj + 0.5f * bwj;
                    float y1j = byj - 0.5f * bhj, y2j = byj + 0.5f * bhj;
                    float aj = bwj * bhj;
                    float iw = fmaxf(fminf(x2j, xi2) - fmaxf(x1j, xi1), 0.0f);
                    float ih = fmaxf(fminf(y2j, yi2) - fmaxf(y1j, yi1), 0.0f);
                    float inter = iw * ih;
                    float iou = inter / ((aj + ai) - inter);
                    if (iou >= 0.45f) sobj[j] = 0.0f;
                }
            }
            __syncthreads();
        }
    }
}

__global__ __launch_bounds__(256) void epi_kernel(
    float* __restrict__ det,
    const unsigned short* __restrict__ order_g,
    const float* __restrict__ sobj_g,
    const int* __restrict__ nobj_g)
{
#pragma clang fp contract(off)
    const int b = blockIdx.x;
    const int tid = threadIdx.x;
    float* detb = det + (size_t)b * NBOX * 7;
    const unsigned short* ord = order_g + b * NPAD;
    const float* sobj = sobj_g + b * NPAD;
    const int num_obj = nobj_g[b];

    float v0[8], v1[8], v2[8], v3[8], v4[8], v5[8], v6[8], msk[8];
#pragma unroll
    for (int c = 0; c < 8; ++c) {
        int r = tid + c * 256;
        if (r < NBOX) {
            const float* row = detb + (int)ord[r] * 7;
            float obj = row[0], bx = row[1], by = row[2], bw = row[3];
            float bh = row[4], cid = row[5], prob = row[6];
            bool keep = (r < num_obj) && (sobj[r] > 0.01f) && (r != num_obj - 1);
            float p = prob * ((prob > 0.1f) ? 1.0f : 0.0f);
            bool fin = keep && (p > 0.01f) && (bw * bw > 0.0004f);
            v0[c] = obj; v1[c] = bx; v2[c] = by; v3[c] = bw; v4[c] = bh;
            v5[c] = cid; v6[c] = p;
            msk[c] = fin ? 1.0f : 0.0f;
        }
    }
    __syncthreads();
#pragma unroll
    for (int c = 0; c < 8; ++c) {
        int r = tid + c * 256;
        if (r < NBOX) {
            float* o = detb + r * 7;
            o[0] = v0[c] * msk[c];
            o[1] = v1[c] * msk[c];
            o[2] = v2[c] * msk[c];
            o[3] = v3[c] * msk[c];
            o[4] = v4[c] * msk[c];
            o[5] = v5[c] * msk[c];
            o[6] = v6[c] * msk[c];
        }
    }
}

// ---------------------------------------------------------------------------
// Last-resort monolithic kernel (ws < WS_NEEDED).
// ---------------------------------------------------------------------------
__global__ __launch_bounds__(K2T, 1) void nms_kernel(float* __restrict__ det)
{
#pragma clang fp contract(off)
    __shared__ alignas(16) unsigned long long keys[NPAD];
    __shared__ float s_obj[NBOX];
    __shared__ unsigned short order[NBOX];
    __shared__ int num_obj_sh;

    const int b = blockIdx.x;
    const int tid = threadIdx.x;
    float* detb = det + (size_t)b * NBOX * 7;

    for (int n = tid; n < NPAD; n += K2T) {
        if (n < NBOX) {
            unsigned ob = __float_as_uint(detb[n * 7 + 0]);
            keys[n] = ((unsigned long long)ob << 32) | (unsigned long long)(2047 - n);
        } else keys[n] = 0ull;
    }
    if (tid == 0) num_obj_sh = 0;
    __syncthreads();

    for (unsigned k = 2; k <= NPAD; k <<= 1) {
        for (unsigned j = k >> 1; j > 0; j >>= 1) {
            for (unsigned idx = tid; idx < NPAD; idx += K2T) {
                unsigned ixj = idx ^ j;
                if (ixj > idx) {
                    unsigned long long av = keys[idx], bv = keys[ixj];
                    bool up = ((idx & k) == 0);
                    if (up ? (av < bv) : (av > bv)) { keys[idx] = bv; keys[ixj] = av; }
                }
            }
            __syncthreads();
        }
    }

    int cnt = 0;
    for (int r = tid; r < NBOX; r += K2T) {
        unsigned long long kk = keys[r];
        order[r] = (unsigned short)(2047u - (unsigned)(kk & 0xffffffffu));
        float ob = __uint_as_float((unsigned)(kk >> 32));
        s_obj[r] = ob;
        cnt += (ob > 0.5f) ? 1 : 0;
    }
    atomicAdd(&num_obj_sh, cnt);
    __syncthreads();
    const int num_obj = num_obj_sh;

    for (int i = 0; i < num_obj; ++i) {
        if (s_obj[i] > 0.01f) {
            const float* ri = detb + (int)order[i] * 7;
            float bxi = ri[1], byi = ri[2], bwi = ri[3], bhi = ri[4];
            float xi1 = bxi - 0.5f * bwi, xi2 = bxi + 0.5f * bwi;
            float yi1 = byi - 0.5f * bhi, yi2 = byi + 0.5f * bhi;
            float ai = bwi * bhi;
            for (int j = i + 1 + tid; j < num_obj; j += K2T) {
                const float* rj = detb + (int)order[j] * 7;
                float bxj = rj[1], byj = rj[2], bwj = rj[3], bhj = rj[4];
                float x1j = bxj - 0.5f * bwj, x2j = bxj + 0.5f * bwj;
                float y1j = byj - 0.5f * bhj, y2j = byj + 0.5f * bhj;
                float aj = bwj * bhj;
                float iw = fmaxf(fminf(x2j, xi2) - fmaxf(x1j, xi1), 0.0f);
                float ih = fmaxf(fminf(y2j, yi2) - fmaxf(y1j, yi1), 0.0f);
                float inter = iw * ih;
                float iou = inter / ((aj + ai) - inter);
                if (iou >= 0.45f) s_obj[j] = 0.0f;
            }
        }
        __syncthreads();
    }

    float v0[8], v1[8], v2[8], v3[8], v4[8], v5[8], v6[8], msk[8];
#pragma unroll
    for (int c = 0; c < 8; ++c) {
        int r = tid + c * K2T;
        if (r < NBOX) {
            const float* row = detb + (int)order[r] * 7;
            float obj = row[0], bx = row[1], by = row[2], bw = row[3];
            float bh = row[4], cid = row[5], prob = row[6];
            bool keep = (r < num_obj) && (s_obj[r] > 0.01f) && (r != num_obj - 1);
            float p = prob * ((prob > 0.1f) ? 1.0f : 0.0f);
            bool fin = keep && (p > 0.01f) && (bw * bw > 0.0004f);
            v0[c] = obj; v1[c] = bx; v2[c] = by; v3[c] = bw; v4[c] = bh;
            v5[c] = cid; v6[c] = p;
            msk[c] = fin ? 1.0f : 0.0f;
        }
    }
    __syncthreads();
#pragma unroll
    for (int c = 0; c < 8; ++c) {
        int r = tid + c * K2T;
        if (r < NBOX) {
            float* o = detb + r * 7;
            o[0] = v0[c] * msk[c]; o[1] = v1[c] * msk[c]; o[2] = v2[c] * msk[c];
            o[3] = v3[c] * msk[c]; o[4] = v4[c] * msk[c]; o[5] = v5[c] * msk[c];
            o[6] = v6[c] * msk[c];
        }
    }
}

extern "C" void kernel_launch(void* const* d_in, const int* in_sizes, int n_in,
                              void* d_out, int out_size, void* d_ws, size_t ws_size,
                              hipStream_t stream)
{
    const float* pred    = (const float*)d_in[0];
    const float* anchors = (const float*)d_in[1];
    float* out = (float*)d_out;

    int total = NBATCH * NBOX;
    int blocks = (total + 255) / 256;
    decode_kernel<<<blocks, 256, 0, stream>>>(pred, anchors, out);

    if (ws_size >= WS_NEEDED) {
        char* ws = (char*)d_ws;
        int*            nobj  = (int*)(ws + WS_NUMOBJ_OFF);
        unsigned short* order = (unsigned short*)(ws + WS_ORDER_OFF);
        float*          sobj  = (float*)(ws + WS_SOBJ_OFF);
        sort_kernel<<<NBATCH, 1024, 0, stream>>>(out, order, sobj, nobj);
        if (ws_size >= WS_NEEDED2) {
            unsigned long long* sup  = (unsigned long long*)(ws + WS_SUP_OFF);
            unsigned long long* drow = (unsigned long long*)(ws + WS_DROW_OFF);
            sup_kernel<<<NBATCH * NSPLIT, 1024, 0, stream>>>(out, order, nobj, sup, drow);
            scanepi_kernel<<<NBATCH, 256, 0, stream>>>(out, order, sobj, nobj, sup, drow);
        } else {
            nms4_kernel<<<NBATCH, 1024, 0, stream>>>(out, order, sobj, nobj);
            epi_kernel<<<NBATCH, 256, 0, stream>>>(out, order, sobj, nobj);
        }
    } else {
        nms_kernel<<<NBATCH, K2T, 0, stream>>>(out);
    }
}

// Round 12
// 143.144 us; speedup vs baseline: 2.2785x; 1.1319x over previous
//
#include <hip/hip_runtime.h>

#define NUMA 5
#define NCLS 80
#define AL 85          // 80 + 4 + 1
#define HW 361         // 19*19
#define NBOX 1805      // 5*361
#define NBATCH 128
#define NPAD 2048
#define K2T 256
#define MCAP 1024      // two-phase cap on num_obj (expected ~902 +/- 21)
#define NCHUNK 16      // MCAP / 64
#define NSPLIT 4       // phase-1 blocks per image

// ---- d_ws layout ----
#define WS_NUMOBJ_OFF 0                                  // int32 [128]
#define WS_ORDER_OFF  512                                // u16   [128][2048]
#define WS_SOBJ_OFF   (512 + NBATCH * NPAD * 2)          // f32   [128][2048]
#define WS_NEEDED     ((size_t)(WS_SOBJ_OFF + NBATCH * NPAD * 4))   // ~1.5 MB
#define WS_SUP_OFF    WS_NEEDED                          // u64 [128][16][1024]
#define WS_DROW_OFF   (WS_SUP_OFF + (size_t)NBATCH * NCHUNK * MCAP * 8)
#define WS_NEEDED2    (WS_DROW_OFF + (size_t)NBATCH * NCHUNK * 64 * 8)  // ~19.3 MB
#define WS_DETW_OFF   WS_NEEDED2                         // f32 [128][1805][7]
#define WS_NEEDED3    (WS_DETW_OFF + (size_t)NBATCH * NBOX * 7 * 4)     // ~25.8 MB

// Exact-division-compare constant: MID = (0.45f + pred(0.45f))/2 exactly.
// RN32(inter/denom) >= 0.45f  <=>  fma64(denom, MID, -inter) <= 0 (exact sign)
#define MID_CONST (30198987.0 / 67108864.0)

__device__ __forceinline__ unsigned long long bcast64(unsigned long long v, int t) {
    unsigned lo = (unsigned)__builtin_amdgcn_readlane((int)(unsigned)v, t);
    unsigned hi = (unsigned)__builtin_amdgcn_readlane((int)(unsigned)(v >> 32), t);
    return ((unsigned long long)hi << 32) | (unsigned long long)lo;
}

// ---------------------------------------------------------------------------
// Kernel 1: decode.  pred [B, 425, 19, 19] -> det [B, 1805, 7] written to out
// ---------------------------------------------------------------------------
__global__ __launch_bounds__(256) void decode_kernel(
    const float* __restrict__ pred,
    const float* __restrict__ anchors,
    float* __restrict__ det)
{
#pragma clang fp contract(off)
    int id = blockIdx.x * blockDim.x + threadIdx.x;
    if (id >= NBATCH * NBOX) return;
    int b = id / NBOX;
    int r = id - b * NBOX;
    int a = r / HW;
    int s = r - a * HW;
    int ci = s % 19;
    int cj = s / 19;

    const float* base = pred + ((size_t)(b * (NUMA * AL) + a * AL) * HW + s);
    float tx  = base[0 * HW];
    float ty  = base[1 * HW];
    float tw  = base[2 * HW];
    float th  = base[3 * HW];
    float obj = base[4 * HW];

    float cmax = base[5 * HW];
    int karg = 0;
#pragma unroll 4
    for (int k = 1; k < NCLS; ++k) {
        float c = base[(5 + k) * HW];
        if (c > cmax) { cmax = c; karg = k; }
    }

    float bx = (tx + (float)ci) / 19.0f;
    float by = (ty + (float)cj) / 19.0f;
    float aw = anchors[2 * a];
    float ah = anchors[2 * a + 1];
    float bw = expf(tw) * (aw / 19.0f);
    float bh = expf(th) * (ah / 19.0f);
    float prob = cmax * obj;
    float cid  = (float)karg;

    float* o = det + (size_t)(b * NBOX + r) * 7;
    o[0] = obj; o[1] = bx; o[2] = by; o[3] = bw; o[4] = bh; o[5] = cid; o[6] = prob;
}

// ---------------------------------------------------------------------------
// Kernel 2: per-image stable bitonic sort (desc by obj). 1024 threads/image.
// Optionally also writes detws[r] = detb[ord[r]] (sorted-order det copy).
// ---------------------------------------------------------------------------
__global__ __launch_bounds__(1024) void sort_kernel(
    const float* __restrict__ det,
    unsigned short* __restrict__ order_g,
    float* __restrict__ sobj_g,
    int* __restrict__ nobj_g,
    float* __restrict__ detws)               // may be nullptr
{
    __shared__ unsigned long long keys[NPAD];
    __shared__ int cnt_sh;
    const int b = blockIdx.x;
    const int tid = threadIdx.x;
    const float* detb = det + (size_t)b * NBOX * 7;

    for (int n = tid; n < NPAD; n += 1024) {
        keys[n] = (n < NBOX)
            ? (((unsigned long long)__float_as_uint(detb[n * 7]) << 32)
               | (unsigned long long)(2047 - n))
            : 0ull;
    }
    if (tid == 0) cnt_sh = 0;
    __syncthreads();

    for (unsigned k = 2; k <= NPAD; k <<= 1) {
        for (unsigned j = k >> 1; j > 0; j >>= 1) {
            for (unsigned idx = tid; idx < NPAD; idx += 1024) {
                unsigned ixj = idx ^ j;
                if (ixj > idx) {
                    unsigned long long av = keys[idx], bv = keys[ixj];
                    bool up = ((idx & k) == 0);
                    if (up ? (av < bv) : (av > bv)) { keys[idx] = bv; keys[ixj] = av; }
                }
            }
            __syncthreads();
        }
    }

    int cnt = 0;
    for (int r = tid; r < NBOX; r += 1024) {
        unsigned long long kk = keys[r];
        int idx = 2047 - (int)(unsigned)(kk & 0xffffffffu);
        order_g[b * NPAD + r] = (unsigned short)idx;
        float ob = __uint_as_float((unsigned)(kk >> 32));
        sobj_g[b * NPAD + r] = ob;
        cnt += (ob > 0.5f) ? 1 : 0;
        if (detws) {
            const float* src = detb + idx * 7;
            float* dst = detws + ((size_t)b * NBOX + r) * 7;
#pragma unroll
            for (int q = 0; q < 7; ++q) dst[q] = src[q];
        }
    }
    atomicAdd(&cnt_sh, cnt);
    __syncthreads();
    if (tid == 0) nobj_g[b] = cnt_sh;
}

// ---------------------------------------------------------------------------
// Kernel 3a: suppression-matrix build. Grid = 128 * NSPLIT blocks. Each block
// stages boxes in 20 KB LDS, computes its share of the 136 chunk-pair tiles,
// writes SUP columns (+ diagonal DROW) to d_ws.
// ---------------------------------------------------------------------------
__global__ __launch_bounds__(1024) void sup_kernel(
    const float* __restrict__ det,
    const unsigned short* __restrict__ order_g,
    const int* __restrict__ nobj_g,
    unsigned long long* __restrict__ sup_g,
    unsigned long long* __restrict__ drow_g)
{
#pragma clang fp contract(off)
    __shared__ float4 QS[MCAP];                          // 16 KB
    __shared__ float  AS[MCAP];                          // 4 KB
    const int bb = blockIdx.x;
    const int b = bb / NSPLIT;
    const int part = bb - b * NSPLIT;
    const int tid = threadIdx.x;
    const int lane = tid & 63;
    const int wv = tid >> 6;
    const int num_obj = nobj_g[b];
    if (num_obj > MCAP) return;                          // fallback handles
    const int M = num_obj;
    const float* detb = det + (size_t)b * NBOX * 7;
    const unsigned short* ord = order_g + b * NPAD;

    {
        const float* row = detb + (int)ord[tid] * 7;
        float bx = row[1], by = row[2], bw = row[3], bh = row[4];
        QS[tid] = make_float4(bx - 0.5f * bw, by - 0.5f * bh,
                              bx + 0.5f * bw, by + 0.5f * bh);
        AS[tid] = bw * bh;
    }
    __syncthreads();

    for (int k = part * 16 + wv; k < 136; k += 16 * NSPLIT) {
        int c2 = 0;
        while ((c2 + 1) * (c2 + 2) / 2 <= k) ++c2;       // tile -> (c2, cc<=c2)
        int cc = k - c2 * (c2 + 1) / 2;
        if (c2 * 64 < M) {
            int j = c2 * 64 + lane;
            float4 qj = QS[j];
            float  aj = AS[j];
            unsigned long long w = 0ull;
            if (cc == c2) {
                unsigned long long myrow = 0ull;
                for (int t = 0; t < 64; ++t) {
                    float4 qt = QS[cc * 64 + t];
                    float  at = AS[cc * 64 + t];
                    float iw = fmaxf(fminf(qj.z, qt.z) - fmaxf(qj.x, qt.x), 0.0f);
                    float ih = fmaxf(fminf(qj.w, qt.w) - fmaxf(qj.y, qt.y), 0.0f);
                    float inter = iw * ih;
                    float denom = (aj + at) - inter;
                    bool supp = (fma((double)denom, MID_CONST,
                                     -(double)inter) <= 0.0) && (t < lane);
                    unsigned long long bb2 = __ballot(supp);
                    w |= supp ? (1ull << t) : 0ull;
                    if (lane == t) myrow = bb2;
                }
                drow_g[((size_t)b * NCHUNK + cc) * 64 + lane] = myrow;
            } else {
#pragma unroll 8
                for (int t = 0; t < 64; ++t) {
                    float4 qt = QS[cc * 64 + t];
                    float  at = AS[cc * 64 + t];
                    float iw = fmaxf(fminf(qj.z, qt.z) - fmaxf(qj.x, qt.x), 0.0f);
                    float ih = fmaxf(fminf(qj.w, qt.w) - fmaxf(qj.y, qt.y), 0.0f);
                    float inter = iw * ih;
                    float denom = (aj + at) - inter;
                    bool supp = (fma((double)denom, MID_CONST,
                                     -(double)inter) <= 0.0);
                    w |= supp ? (1ull << t) : 0ull;
                }
            }
            sup_g[((size_t)b * NCHUNK + cc) * MCAP + j] = w;
        }
    }
}

// ---------------------------------------------------------------------------
// Kernel 3b (tier 3): greedy scan only. 256 threads/image: 4 waves stage the
// full SUP (128 KB) + DROW into LDS coalesced; wave 0 scans from LDS and
// zeroes suppressed sobj entries. Fallback (num_obj > MCAP): serial greedy
// over the coalesced sorted det copy.
// ---------------------------------------------------------------------------
__global__ __launch_bounds__(256) void scan_kernel(
    const float* __restrict__ detws,
    float* __restrict__ sobj_g,
    const int* __restrict__ nobj_g,
    const unsigned long long* __restrict__ sup_g,
    const unsigned long long* __restrict__ drow_g)
{
#pragma clang fp contract(off)
    __shared__ unsigned long long SUPL[NCHUNK][MCAP];    // 128 KB
    __shared__ unsigned long long DR[NCHUNK][64];        // 8 KB
    const int b = blockIdx.x;
    const int tid = threadIdx.x;
    const int lane = tid & 63;
    float* sobj = sobj_g + b * NPAD;
    const int num_obj = nobj_g[b];
    const int M = (num_obj < MCAP) ? num_obj : MCAP;

    if (num_obj <= MCAP) {
        // stage SUP + DROW coalesced (independent loads, 4 waves)
        const unsigned long long* supb = sup_g + (size_t)b * NCHUNK * MCAP;
#pragma unroll
        for (int i = 0; i < 64; ++i)
            ((unsigned long long*)SUPL)[tid + i * 256] = supb[tid + i * 256];
#pragma unroll
        for (int i = 0; i < 4; ++i)
            ((unsigned long long*)DR)[tid + i * 256] =
                drow_g[(size_t)b * NCHUNK * 64 + tid + i * 256];
        __syncthreads();

        if (tid < 64) {
            unsigned rm = 0u;                  // bit c = my box in chunk c dead
            for (int c = 0; c < NCHUNK && c * 64 < M; ++c) {
                int rem_in = M - c * 64;
                unsigned long long cmask =
                    (rem_in >= 64) ? ~0ull : ((1ull << rem_in) - 1ull);
                unsigned long long deadw = __ballot((rm >> c) & 1u);
                unsigned long long rowreg = DR[c][lane];
                unsigned long long rem = cmask & ~deadw;
                const unsigned long long rem0 = rem;
                unsigned long long S = 0ull;   // survivors of chunk c
                while (rem) {
                    int t = (int)__builtin_ctzll(rem);
                    S |= (1ull << t);
                    unsigned long long row_t = bcast64(rowreg, t);
                    rem &= ~row_t;
                    rem &= ~(1ull << t);
                }
                unsigned long long deadnew = rem0 & ~S;
                rm |= (unsigned)((deadnew >> lane) & 1ull) << c;
                for (int c2 = c + 1; c2 < NCHUNK && c2 * 64 < M; ++c2) {
                    unsigned long long w2 = SUPL[c][c2 * 64 + lane];
                    rm |= ((w2 & S) != 0ull) ? (1u << c2) : 0u;
                }
            }
#pragma unroll
            for (int c2 = 0; c2 < NCHUNK; ++c2) {
                int j = c2 * 64 + lane;
                if (j < M && ((rm >> c2) & 1u)) sobj[j] = 0.0f;
            }
        }
    } else {
        // fallback: serial greedy over coalesced sorted rows
        const float* dws = detws + (size_t)b * NBOX * 7;
        for (int i = 0; i < num_obj; ++i) {
            if (sobj[i] > 0.01f) {
                const float* ri = dws + i * 7;
                float bxi = ri[1], byi = ri[2], bwi = ri[3], bhi = ri[4];
                float xi1 = bxi - 0.5f * bwi, xi2 = bxi + 0.5f * bwi;
                float yi1 = byi - 0.5f * bhi, yi2 = byi + 0.5f * bhi;
                float ai = bwi * bhi;
                for (int j = i + 1 + tid; j < num_obj; j += 256) {
                    const float* rj = dws + j * 7;
                    float bxj = rj[1], byj = rj[2], bwj = rj[3], bhj = rj[4];
                    float x1j = bxj - 0.5f * bwj, x2j = bxj + 0.5f * bwj;
                    float y1j = byj - 0.5f * bhj, y2j = byj + 0.5f * bhj;
                    float aj = bwj * bhj;
                    float iw = fmaxf(fminf(x2j, xi2) - fmaxf(x1j, xi1), 0.0f);
                    float ih = fmaxf(fminf(y2j, yi2) - fmaxf(y1j, yi1), 0.0f);
                    float inter = iw * ih;
                    float iou = inter / ((aj + ai) - inter);
                    if (iou >= 0.45f) sobj[j] = 0.0f;
                }
            }
            __syncthreads();
        }
    }
}

// ---------------------------------------------------------------------------
// Kernel 4 (tier 3): flat-parallel epilogue. One thread per output row.
// Reads sorted-order rows from detws (coalesced), writes det (coalesced).
// ---------------------------------------------------------------------------
__global__ __launch_bounds__(256) void epi2_kernel(
    float* __restrict__ det,
    const float* __restrict__ detws,
    const float* __restrict__ sobj_g,
    const int* __restrict__ nobj_g)
{
#pragma clang fp contract(off)
    int row = blockIdx.x * blockDim.x + threadIdx.x;
    if (row >= NBATCH * NBOX) return;
    int b = row / NBOX;
    int r = row - b * NBOX;
    const int num_obj = nobj_g[b];
    const float* src = detws + (size_t)row * 7;
    float obj = src[0], bx = src[1], by = src[2], bw = src[3];
    float bh = src[4], cid = src[5], prob = src[6];
    float s = sobj_g[b * NPAD + r];
    bool keep = (r < num_obj) && (s > 0.01f) && (r != num_obj - 1);
    float p = prob * ((prob > 0.1f) ? 1.0f : 0.0f);
    bool fin = keep && (p > 0.01f) && (bw * bw > 0.0004f);
    float m = fin ? 1.0f : 0.0f;
    float* o = det + (size_t)row * 7;
    o[0] = obj * m; o[1] = bx * m; o[2] = by * m; o[3] = bw * m;
    o[4] = bh * m; o[5] = cid * m; o[6] = p * m;
}

// ---------------------------------------------------------------------------
// Tier-2 fused scan+epilogue (round 11) -- kept for 19.3MB <= ws < 25.8MB.
// ---------------------------------------------------------------------------
__global__ __launch_bounds__(256) void scanepi_kernel(
    float* __restrict__ det,
    const unsigned short* __restrict__ order_g,
    const float* __restrict__ sobj_g,
    const int* __restrict__ nobj_g,
    const unsigned long long* __restrict__ sup_g,
    const unsigned long long* __restrict__ drow_g)
{
#pragma clang fp contract(off)
    __shared__ float sobj_l[NPAD];
    __shared__ unsigned long long DR[NCHUNK][64];
    const int b = blockIdx.x;
    const int tid = threadIdx.x;
    const int lane = tid & 63;
    float* detb = det + (size_t)b * NBOX * 7;
    const unsigned short* ord = order_g + b * NPAD;
    const int num_obj = nobj_g[b];
    const int M = (num_obj < MCAP) ? num_obj : MCAP;

#pragma unroll
    for (int c = 0; c < 8; ++c) sobj_l[tid + c * 256] = sobj_g[b * NPAD + tid + c * 256];
    if (num_obj <= MCAP) {
#pragma unroll
        for (int c = 0; c < 4; ++c) {
            int i = tid + c * 256;
            ((unsigned long long*)DR)[i] = drow_g[(size_t)b * NCHUNK * 64 + i];
        }
    }
    __syncthreads();

    if (num_obj <= MCAP) {
        if (tid < 64) {
            unsigned rm = 0u;
            for (int c = 0; c < NCHUNK && c * 64 < M; ++c) {
                int rem_in = M - c * 64;
                unsigned long long cmask =
                    (rem_in >= 64) ? ~0ull : ((1ull << rem_in) - 1ull);
                unsigned long long deadw = __ballot((rm >> c) & 1u);
                unsigned long long rowreg = DR[c][lane];
                unsigned long long rem = cmask & ~deadw;
                const unsigned long long rem0 = rem;
                unsigned long long S = 0ull;
                while (rem) {
                    int t = (int)__builtin_ctzll(rem);
                    S |= (1ull << t);
                    unsigned long long row_t = bcast64(rowreg, t);
                    rem &= ~row_t;
                    rem &= ~(1ull << t);
                }
                unsigned long long deadnew = rem0 & ~S;
                rm |= (unsigned)((deadnew >> lane) & 1ull) << c;
                const unsigned long long* supc =
                    sup_g + ((size_t)b * NCHUNK + c) * MCAP;
                for (int c2 = c + 1; c2 < NCHUNK && c2 * 64 < M; ++c2) {
                    unsigned long long w2 = supc[c2 * 64 + lane];
                    rm |= ((w2 & S) != 0ull) ? (1u << c2) : 0u;
                }
            }
#pragma unroll
            for (int c2 = 0; c2 < NCHUNK; ++c2) {
                int j = c2 * 64 + lane;
                if (j < M && ((rm >> c2) & 1u)) sobj_l[j] = 0.0f;
            }
        }
        __syncthreads();
    } else {
        for (int i = 0; i < num_obj; ++i) {
            if (sobj_l[i] > 0.01f) {
                const float* ri = detb + (int)ord[i] * 7;
                float bxi = ri[1], byi = ri[2], bwi = ri[3], bhi = ri[4];
                float xi1 = bxi - 0.5f * bwi, xi2 = bxi + 0.5f * bwi;
                float yi1 = byi - 0.5f * bhi, yi2 = byi + 0.5f * bhi;
                float ai = bwi * bhi;
                for (int j = i + 1 + tid; j < num_obj; j += 256) {
                    const float* rj = detb + (int)ord[j] * 7;
                    float bxj = rj[1], byj = rj[2], bwj = rj[3], bhj = rj[4];
                    float x1j = bxj - 0.5f * bwj, x2j = bxj + 0.5f * bwj;
                    float y1j = byj - 0.5f * bhj, y2j = byj + 0.5f * bhj;
                    float aj = bwj * bhj;
                    float iw = fmaxf(fminf(x2j, xi2) - fmaxf(x1j, xi1), 0.0f);
                    float ih = fmaxf(fminf(y2j, yi2) - fmaxf(y1j, yi1), 0.0f);
                    float inter = iw * ih;
                    float iou = inter / ((aj + ai) - inter);
                    if (iou >= 0.45f) sobj_l[j] = 0.0f;
                }
            }
            __syncthreads();
        }
    }

    float v0[8], v1[8], v2[8], v3[8], v4[8], v5[8], v6[8], msk[8];
#pragma unroll
    for (int c = 0; c < 8; ++c) {
        int r = tid + c * 256;
        if (r < NBOX) {
            const float* row = detb + (int)ord[r] * 7;
            float obj = row[0], bx = row[1], by = row[2], bw = row[3];
            float bh = row[4], cid = row[5], prob = row[6];
            bool keep = (r < num_obj) && (sobj_l[r] > 0.01f) && (r != num_obj - 1);
            float p = prob * ((prob > 0.1f) ? 1.0f : 0.0f);
            bool fin = keep && (p > 0.01f) && (bw * bw > 0.0004f);
            v0[c] = obj; v1[c] = bx; v2[c] = by; v3[c] = bw; v4[c] = bh;
            v5[c] = cid; v6[c] = p;
            msk[c] = fin ? 1.0f : 0.0f;
        }
    }
    __syncthreads();
#pragma unroll
    for (int c = 0; c < 8; ++c) {
        int r = tid + c * 256;
        if (r < NBOX) {
            float* o = detb + r * 7;
            o[0] = v0[c] * msk[c]; o[1] = v1[c] * msk[c]; o[2] = v2[c] * msk[c];
            o[3] = v3[c] * msk[c]; o[4] = v4[c] * msk[c]; o[5] = v5[c] * msk[c];
            o[6] = v6[c] * msk[c];
        }
    }
}

// ---------------------------------------------------------------------------
// Tier-1 fallback (1.5MB <= ws < 19.3MB): monolithic two-phase NMS + epi.
// ---------------------------------------------------------------------------
__global__ __launch_bounds__(1024, 1) void nms4_kernel(
    const float* __restrict__ det,
    const unsigned short* __restrict__ order_g,
    float* __restrict__ sobj_g,
    const int* __restrict__ nobj_g)
{
#pragma clang fp contract(off)
    __shared__ float4 QS[MCAP];
    __shared__ float  AS[MCAP];
    __shared__ unsigned long long SUP[NCHUNK][MCAP];
    __shared__ unsigned long long DROW[NCHUNK][64];
    const int b = blockIdx.x;
    const int tid = threadIdx.x;
    const int lane = tid & 63;
    const int wv = tid >> 6;
    const float* detb = det + (size_t)b * NBOX * 7;
    const unsigned short* ord = order_g + b * NPAD;
    float* sobj = sobj_g + b * NPAD;
    const int num_obj = nobj_g[b];
    const int M = (num_obj < MCAP) ? num_obj : MCAP;

    if (num_obj <= MCAP) {
        {
            const float* row = detb + (int)ord[tid] * 7;
            float bx = row[1], by = row[2], bw = row[3], bh = row[4];
            QS[tid] = make_float4(bx - 0.5f * bw, by - 0.5f * bh,
                                  bx + 0.5f * bw, by + 0.5f * bh);
            AS[tid] = bw * bh;
        }
        __syncthreads();

        for (int k = wv; k < 136; k += 16) {
            int c2 = 0;
            while ((c2 + 1) * (c2 + 2) / 2 <= k) ++c2;
            int cc = k - c2 * (c2 + 1) / 2;
            if (c2 * 64 < M) {
                int j = c2 * 64 + lane;
                float4 qj = QS[j];
                float  aj = AS[j];
                unsigned long long w = 0ull;
                if (cc == c2) {
                    unsigned long long myrow = 0ull;
                    for (int t = 0; t < 64; ++t) {
                        float4 qt = QS[cc * 64 + t];
                        float  at = AS[cc * 64 + t];
                        float iw = fmaxf(fminf(qj.z, qt.z) - fmaxf(qj.x, qt.x), 0.0f);
                        float ih = fmaxf(fminf(qj.w, qt.w) - fmaxf(qj.y, qt.y), 0.0f);
                        float inter = iw * ih;
                        float denom = (aj + at) - inter;
                        bool supp = (fma((double)denom, MID_CONST,
                                         -(double)inter) <= 0.0) && (t < lane);
                        unsigned long long bb = __ballot(supp);
                        w |= supp ? (1ull << t) : 0ull;
                        if (lane == t) myrow = bb;
                    }
                    DROW[cc][lane] = myrow;
                } else {
#pragma unroll 8
                    for (int t = 0; t < 64; ++t) {
                        float4 qt = QS[cc * 64 + t];
                        float  at = AS[cc * 64 + t];
                        float iw = fmaxf(fminf(qj.z, qt.z) - fmaxf(qj.x, qt.x), 0.0f);
                        float ih = fmaxf(fminf(qj.w, qt.w) - fmaxf(qj.y, qt.y), 0.0f);
                        float inter = iw * ih;
                        float denom = (aj + at) - inter;
                        bool supp = (fma((double)denom, MID_CONST,
                                         -(double)inter) <= 0.0);
                        w |= supp ? (1ull << t) : 0ull;
                    }
                }
                SUP[cc][j] = w;
            }
        }
        __syncthreads();

        if (wv == 0) {
            unsigned rm = 0u;
            for (int c = 0; c < NCHUNK && c * 64 < M; ++c) {
                int rem_in = M - c * 64;
                unsigned long long cmask =
                    (rem_in >= 64) ? ~0ull : ((1ull << rem_in) - 1ull);
                unsigned long long deadw = __ballot((rm >> c) & 1u);
                unsigned long long rowreg = DROW[c][lane];
                unsigned long long rem = cmask & ~deadw;
                const unsigned long long rem0 = rem;
                unsigned long long S = 0ull;
                while (rem) {
                    int t = (int)__builtin_ctzll(rem);
                    S |= (1ull << t);
                    unsigned long long row_t = bcast64(rowreg, t);
                    rem &= ~row_t;
                    rem &= ~(1ull << t);
                }
                unsigned long long deadnew = rem0 & ~S;
                rm |= (unsigned)((deadnew >> lane) & 1ull) << c;
                for (int c2 = c + 1; c2 < NCHUNK && c2 * 64 < M; ++c2) {
                    unsigned long long w2 = SUP[c][c2 * 64 + lane];
                    rm |= ((w2 & S) != 0ull) ? (1u << c2) : 0u;
                }
            }
            for (int c2 = 0; c2 < NCHUNK; ++c2) {
                int j = c2 * 64 + lane;
                if (j < M && ((rm >> c2) & 1u)) sobj[j] = 0.0f;
            }
        }
    } else {
        for (int i = 0; i < num_obj; ++i) {
            if (sobj[i] > 0.01f) {
                const float* ri = detb + (int)ord[i] * 7;
                float bxi = ri[1], byi = ri[2], bwi = ri[3], bhi = ri[4];
                float xi1 = bxi - 0.5f * bwi, xi2 = bxi + 0.5f * bwi;
                float yi1 = byi - 0.5f * bhi, yi2 = byi + 0.5f * bhi;
                float ai = bwi * bhi;
                for (int j = i + 1 + tid; j < num_obj; j += 1024) {
                    const float* rj = detb + (int)ord[j] * 7;
                    float bxj = rj[1], byj = rj[2], bwj = rj[3], bhj = rj[4];
                    float x1j = bxj - 0.5f * bwj, x2j = bxj + 0.5f * bwj;
                    float y1j = byj - 0.5f * bhj, y2j = byj + 0.5f * bhj;
                    float aj = bwj * bhj;
                    float iw = fmaxf(fminf(x2j, xi2) - fmaxf(x1j, xi1), 0.0f);
                    float ih = fmaxf(fminf(y2j, yi2) - fmaxf(y1j, yi1), 0.0f);
                    float inter = iw * ih;
                    float iou = inter / ((aj + ai) - inter);
                    if (iou >= 0.45f) sobj[j] = 0.0f;
                }
            }
            __syncthreads();
        }
    }
}

__global__ __launch_bounds__(256) void epi_kernel(
    float* __restrict__ det,
    const unsigned short* __restrict__ order_g,
    const float* __restrict__ sobj_g,
    const int* __restrict__ nobj_g)
{
#pragma clang fp contract(off)
    const int b = blockIdx.x;
    const int tid = threadIdx.x;
    float* detb = det + (size_t)b * NBOX * 7;
    const unsigned short* ord = order_g + b * NPAD;
    const float* sobj = sobj_g + b * NPAD;
    const int num_obj = nobj_g[b];

    float v0[8], v1[8], v2[8], v3[8], v4[8], v5[8], v6[8], msk[8];
#pragma unroll
    for (int c = 0; c < 8; ++c) {
        int r = tid + c * 256;
        if (r < NBOX) {
            const float* row = detb + (int)ord[r] * 7;
            float obj = row[0], bx = row[1], by = row[2], bw = row[3];
            float bh = row[4], cid = row[5], prob = row[6];
            bool keep = (r < num_obj) && (sobj[r] > 0.01f) && (r != num_obj - 1);
            float p = prob * ((prob > 0.1f) ? 1.0f : 0.0f);
            bool fin = keep && (p > 0.01f) && (bw * bw > 0.0004f);
            v0[c] = obj; v1[c] = bx; v2[c] = by; v3[c] = bw; v4[c] = bh;
            v5[c] = cid; v6[c] = p;
            msk[c] = fin ? 1.0f : 0.0f;
        }
    }
    __syncthreads();
#pragma unroll
    for (int c = 0; c < 8; ++c) {
        int r = tid + c * 256;
        if (r < NBOX) {
            float* o = detb + r * 7;
            o[0] = v0[c] * msk[c];
            o[1] = v1[c] * msk[c];
            o[2] = v2[c] * msk[c];
            o[3] = v3[c] * msk[c];
            o[4] = v4[c] * msk[c];
            o[5] = v5[c] * msk[c];
            o[6] = v6[c] * msk[c];
        }
    }
}

// ---------------------------------------------------------------------------
// Last-resort monolithic kernel (ws < WS_NEEDED).
// ---------------------------------------------------------------------------
__global__ __launch_bounds__(K2T, 1) void nms_kernel(float* __restrict__ det)
{
#pragma clang fp contract(off)
    __shared__ alignas(16) unsigned long long keys[NPAD];
    __shared__ float s_obj[NBOX];
    __shared__ unsigned short order[NBOX];
    __shared__ int num_obj_sh;

    const int b = blockIdx.x;
    const int tid = threadIdx.x;
    float* detb = det + (size_t)b * NBOX * 7;

    for (int n = tid; n < NPAD; n += K2T) {
        if (n < NBOX) {
            unsigned ob = __float_as_uint(detb[n * 7 + 0]);
            keys[n] = ((unsigned long long)ob << 32) | (unsigned long long)(2047 - n);
        } else keys[n] = 0ull;
    }
    if (tid == 0) num_obj_sh = 0;
    __syncthreads();

    for (unsigned k = 2; k <= NPAD; k <<= 1) {
        for (unsigned j = k >> 1; j > 0; j >>= 1) {
            for (unsigned idx = tid; idx < NPAD; idx += K2T) {
                unsigned ixj = idx ^ j;
                if (ixj > idx) {
                    unsigned long long av = keys[idx], bv = keys[ixj];
                    bool up = ((idx & k) == 0);
                    if (up ? (av < bv) : (av > bv)) { keys[idx] = bv; keys[ixj] = av; }
                }
            }
            __syncthreads();
        }
    }

    int cnt = 0;
    for (int r = tid; r < NBOX; r += K2T) {
        unsigned long long kk = keys[r];
        order[r] = (unsigned short)(2047u - (unsigned)(kk & 0xffffffffu));
        float ob = __uint_as_float((unsigned)(kk >> 32));
        s_obj[r] = ob;
        cnt += (ob > 0.5f) ? 1 : 0;
    }
    atomicAdd(&num_obj_sh, cnt);
    __syncthreads();
    const int num_obj = num_obj_sh;

    for (int i = 0; i < num_obj; ++i) {
        if (s_obj[i] > 0.01f) {
            const float* ri = detb + (int)order[i] * 7;
            float bxi = ri[1], byi = ri[2], bwi = ri[3], bhi = ri[4];
            float xi1 = bxi - 0.5f * bwi, xi2 = bxi + 0.5f * bwi;
            float yi1 = byi - 0.5f * bhi, yi2 = byi + 0.5f * bhi;
            float ai = bwi * bhi;
            for (int j = i + 1 + tid; j < num_obj; j += K2T) {
                const float* rj = detb + (int)order[j] * 7;
                float bxj = rj[1], byj = rj[2], bwj = rj[3], bhj = rj[4];
                float x1j = bxj - 0.5f * bwj, x2j = bxj + 0.5f * bwj;
                float y1j = byj - 0.5f * bhj, y2j = byj + 0.5f * bhj;
                float aj = bwj * bhj;
                float iw = fmaxf(fminf(x2j, xi2) - fmaxf(x1j, xi1), 0.0f);
                float ih = fmaxf(fminf(y2j, yi2) - fmaxf(y1j, yi1), 0.0f);
                float inter = iw * ih;
                float iou = inter / ((aj + ai) - inter);
                if (iou >= 0.45f) s_obj[j] = 0.0f;
            }
        }
        __syncthreads();
    }

    float v0[8], v1[8], v2[8], v3[8], v4[8], v5[8], v6[8], msk[8];
#pragma unroll
    for (int c = 0; c < 8; ++c) {
        int r = tid + c * K2T;
        if (r < NBOX) {
            const float* row = detb + (int)order[r] * 7;
            float obj = row[0], bx = row[1], by = row[2], bw = row[3];
            float bh = row[4], cid = row[5], prob = row[6];
            bool keep = (r < num_obj) && (s_obj[r] > 0.01f) && (r != num_obj - 1);
            float p = prob * ((prob > 0.1f) ? 1.0f : 0.0f);
            bool fin = keep && (p > 0.01f) && (bw * bw > 0.0004f);
            v0[c] = obj; v1[c] = bx; v2[c] = by; v3[c] = bw; v4[c] = bh;
            v5[c] = cid; v6[c] = p;
            msk[c] = fin ? 1.0f : 0.0f;
        }
    }
    __syncthreads();
#pragma unroll
    for (int c = 0; c < 8; ++c) {
        int r = tid + c * K2T;
        if (r < NBOX) {
            float* o = detb + r * 7;
            o[0] = v0[c] * msk[c]; o[1] = v1[c] * msk[c]; o[2] = v2[c] * msk[c];
            o[3] = v3[c] * msk[c]; o[4] = v4[c] * msk[c]; o[5] = v5[c] * msk[c];
            o[6] = v6[c] * msk[c];
        }
    }
}

extern "C" void kernel_launch(void* const* d_in, const int* in_sizes, int n_in,
                              void* d_out, int out_size, void* d_ws, size_t ws_size,
                              hipStream_t stream)
{
    const float* pred    = (const float*)d_in[0];
    const float* anchors = (const float*)d_in[1];
    float* out = (float*)d_out;

    int total = NBATCH * NBOX;
    int blocks = (total + 255) / 256;
    decode_kernel<<<blocks, 256, 0, stream>>>(pred, anchors, out);

    if (ws_size >= WS_NEEDED) {
        char* ws = (char*)d_ws;
        int*            nobj  = (int*)(ws + WS_NUMOBJ_OFF);
        unsigned short* order = (unsigned short*)(ws + WS_ORDER_OFF);
        float*          sobj  = (float*)(ws + WS_SOBJ_OFF);
        if (ws_size >= WS_NEEDED3) {
            unsigned long long* sup  = (unsigned long long*)(ws + WS_SUP_OFF);
            unsigned long long* drow = (unsigned long long*)(ws + WS_DROW_OFF);
            float*              detw = (float*)(ws + WS_DETW_OFF);
            sort_kernel<<<NBATCH, 1024, 0, stream>>>(out, order, sobj, nobj, detw);
            sup_kernel<<<NBATCH * NSPLIT, 1024, 0, stream>>>(out, order, nobj, sup, drow);
            scan_kernel<<<NBATCH, 256, 0, stream>>>(detw, sobj, nobj, sup, drow);
            epi2_kernel<<<blocks, 256, 0, stream>>>(out, detw, sobj, nobj);
        } else if (ws_size >= WS_NEEDED2) {
            unsigned long long* sup  = (unsigned long long*)(ws + WS_SUP_OFF);
            unsigned long long* drow = (unsigned long long*)(ws + WS_DROW_OFF);
            sort_kernel<<<NBATCH, 1024, 0, stream>>>(out, order, sobj, nobj, nullptr);
            sup_kernel<<<NBATCH * NSPLIT, 1024, 0, stream>>>(out, order, nobj, sup, drow);
            scanepi_kernel<<<NBATCH, 256, 0, stream>>>(out, order, sobj, nobj, sup, drow);
        } else {
            sort_kernel<<<NBATCH, 1024, 0, stream>>>(out, order, sobj, nobj, nullptr);
            nms4_kernel<<<NBATCH, 1024, 0, stream>>>(out, order, sobj, nobj);
            epi_kernel<<<NBATCH, 256, 0, stream>>>(out, order, sobj, nobj);
        }
    } else {
        nms_kernel<<<NBATCH, K2T, 0, stream>>>(out);
    }
}

// Round 13
// 136.859 us; speedup vs baseline: 2.3831x; 1.0459x over previous
//
#include <hip/hip_runtime.h>

#define NUMA 5
#define NCLS 80
#define AL 85          // 80 + 4 + 1
#define HW 361         // 19*19
#define NBOX 1805      // 5*361
#define NBATCH 128
#define NPAD 2048
#define K2T 256
#define MCAP 1024      // two-phase cap on num_obj (expected ~902 +/- 21)
#define NCHUNK 16      // MCAP / 64
#define NSPLIT 4       // phase-1 blocks per image

// ---- d_ws layout ----
#define WS_NUMOBJ_OFF 0                                  // int32 [128]
#define WS_ORDER_OFF  512                                // u16   [128][2048]
#define WS_SOBJ_OFF   (512 + NBATCH * NPAD * 2)          // f32   [128][2048]
#define WS_NEEDED     ((size_t)(WS_SOBJ_OFF + NBATCH * NPAD * 4))   // ~1.5 MB
#define WS_SUP_OFF    WS_NEEDED                          // u64 [128][16][1024]
#define WS_DROW_OFF   (WS_SUP_OFF + (size_t)NBATCH * NCHUNK * MCAP * 8)
#define WS_NEEDED2    (WS_DROW_OFF + (size_t)NBATCH * NCHUNK * 64 * 8)  // ~19.3 MB
#define WS_DETW_OFF   WS_NEEDED2                         // f32 [128][1805][7]
#define WS_NEEDED3    (WS_DETW_OFF + (size_t)NBATCH * NBOX * 7 * 4)     // ~25.8 MB

// Exact-division-compare constant: MID = (0.45f + pred(0.45f))/2 exactly.
// RN32(inter/denom) >= 0.45f  <=>  fma64(denom, MID, -inter) <= 0 (exact sign)
#define MID_CONST (30198987.0 / 67108864.0)

__device__ __forceinline__ unsigned long long bcast64(unsigned long long v, int t) {
    unsigned lo = (unsigned)__builtin_amdgcn_readlane((int)(unsigned)v, t);
    unsigned hi = (unsigned)__builtin_amdgcn_readlane((int)(unsigned)(v >> 32), t);
    return ((unsigned long long)hi << 32) | (unsigned long long)lo;
}

// ---------------------------------------------------------------------------
// Kernel 1: decode.  pred [B, 425, 19, 19] -> det [B, 1805, 7] written to out
// ---------------------------------------------------------------------------
__global__ __launch_bounds__(256) void decode_kernel(
    const float* __restrict__ pred,
    const float* __restrict__ anchors,
    float* __restrict__ det)
{
#pragma clang fp contract(off)
    int id = blockIdx.x * blockDim.x + threadIdx.x;
    if (id >= NBATCH * NBOX) return;
    int b = id / NBOX;
    int r = id - b * NBOX;
    int a = r / HW;
    int s = r - a * HW;
    int ci = s % 19;
    int cj = s / 19;

    const float* base = pred + ((size_t)(b * (NUMA * AL) + a * AL) * HW + s);
    float tx  = base[0 * HW];
    float ty  = base[1 * HW];
    float tw  = base[2 * HW];
    float th  = base[3 * HW];
    float obj = base[4 * HW];

    float cmax = base[5 * HW];
    int karg = 0;
#pragma unroll 4
    for (int k = 1; k < NCLS; ++k) {
        float c = base[(5 + k) * HW];
        if (c > cmax) { cmax = c; karg = k; }
    }

    float bx = (tx + (float)ci) / 19.0f;
    float by = (ty + (float)cj) / 19.0f;
    float aw = anchors[2 * a];
    float ah = anchors[2 * a + 1];
    float bw = expf(tw) * (aw / 19.0f);
    float bh = expf(th) * (ah / 19.0f);
    float prob = cmax * obj;
    float cid  = (float)karg;

    float* o = det + (size_t)(b * NBOX + r) * 7;
    o[0] = obj; o[1] = bx; o[2] = by; o[3] = bw; o[4] = bh; o[5] = cid; o[6] = prob;
}

// ---------------------------------------------------------------------------
// Kernel 2: per-image stable bitonic sort (desc by obj). 1024 threads/image.
// Optionally also writes detws[r] = detb[ord[r]] (sorted-order det copy).
// ---------------------------------------------------------------------------
__global__ __launch_bounds__(1024) void sort_kernel(
    const float* __restrict__ det,
    unsigned short* __restrict__ order_g,
    float* __restrict__ sobj_g,
    int* __restrict__ nobj_g,
    float* __restrict__ detws)               // may be nullptr
{
    __shared__ unsigned long long keys[NPAD];
    __shared__ int cnt_sh;
    const int b = blockIdx.x;
    const int tid = threadIdx.x;
    const float* detb = det + (size_t)b * NBOX * 7;

    for (int n = tid; n < NPAD; n += 1024) {
        keys[n] = (n < NBOX)
            ? (((unsigned long long)__float_as_uint(detb[n * 7]) << 32)
               | (unsigned long long)(2047 - n))
            : 0ull;
    }
    if (tid == 0) cnt_sh = 0;
    __syncthreads();

    for (unsigned k = 2; k <= NPAD; k <<= 1) {
        for (unsigned j = k >> 1; j > 0; j >>= 1) {
            for (unsigned idx = tid; idx < NPAD; idx += 1024) {
                unsigned ixj = idx ^ j;
                if (ixj > idx) {
                    unsigned long long av = keys[idx], bv = keys[ixj];
                    bool up = ((idx & k) == 0);
                    if (up ? (av < bv) : (av > bv)) { keys[idx] = bv; keys[ixj] = av; }
                }
            }
            __syncthreads();
        }
    }

    int cnt = 0;
    for (int r = tid; r < NBOX; r += 1024) {
        unsigned long long kk = keys[r];
        int idx = 2047 - (int)(unsigned)(kk & 0xffffffffu);
        order_g[b * NPAD + r] = (unsigned short)idx;
        float ob = __uint_as_float((unsigned)(kk >> 32));
        sobj_g[b * NPAD + r] = ob;
        cnt += (ob > 0.5f) ? 1 : 0;
        if (detws) {
            const float* src = detb + idx * 7;
            float* dst = detws + ((size_t)b * NBOX + r) * 7;
#pragma unroll
            for (int q = 0; q < 7; ++q) dst[q] = src[q];
        }
    }
    atomicAdd(&cnt_sh, cnt);
    __syncthreads();
    if (tid == 0) nobj_g[b] = cnt_sh;
}

// ---------------------------------------------------------------------------
// Kernel 3a: suppression-matrix build. Grid = 128 * NSPLIT blocks (2/CU).
// Balanced tile assignment: wave gw in [0,64) handles the contiguous range
// [gw*A/64, (gw+1)*A/64) of the A = Mc*(Mc+1)/2 ACTIVE tiles (c2-major
// triangle order lists all active tiles first). Boxes staged coalesced from
// detws when available (tier 3), else via ord gather.
// ---------------------------------------------------------------------------
__global__ __launch_bounds__(1024) void sup_kernel(
    const float* __restrict__ det,
    const unsigned short* __restrict__ order_g,
    const int* __restrict__ nobj_g,
    unsigned long long* __restrict__ sup_g,
    unsigned long long* __restrict__ drow_g,
    const float* __restrict__ detws)         // may be nullptr
{
#pragma clang fp contract(off)
    __shared__ float4 QS[MCAP];                          // 16 KB
    __shared__ float  AS[MCAP];                          // 4 KB
    const int bb = blockIdx.x;
    const int b = bb / NSPLIT;
    const int part = bb - b * NSPLIT;
    const int tid = threadIdx.x;
    const int lane = tid & 63;
    const int wv = tid >> 6;
    const int num_obj = nobj_g[b];
    if (num_obj > MCAP) return;                          // fallback handles
    const int M = num_obj;
    const int Mc = (M + 63) >> 6;                        // active chunks
    const int Atiles = Mc * (Mc + 1) / 2;                // active tiles

    // stage boxes
    if (detws) {
        const float* src = detws + ((size_t)b * NBOX + tid) * 7;   // coalesced
        float bx = src[1], by = src[2], bw = src[3], bh = src[4];
        QS[tid] = make_float4(bx - 0.5f * bw, by - 0.5f * bh,
                              bx + 0.5f * bw, by + 0.5f * bh);
        AS[tid] = bw * bh;
    } else {
        const float* row = det + (size_t)b * NBOX * 7
                         + (int)order_g[b * NPAD + tid] * 7;
        float bx = row[1], by = row[2], bw = row[3], bh = row[4];
        QS[tid] = make_float4(bx - 0.5f * bw, by - 0.5f * bh,
                              bx + 0.5f * bw, by + 0.5f * bh);
        AS[tid] = bw * bh;
    }
    __syncthreads();

    const int gw = part * 16 + wv;                       // 0..63
    const int ks = (gw * Atiles) >> 6;
    const int ke = ((gw + 1) * Atiles) >> 6;
    for (int k = ks; k < ke; ++k) {
        int c2 = 0;
        while ((c2 + 1) * (c2 + 2) / 2 <= k) ++c2;       // tile -> (c2, cc<=c2)
        int cc = k - c2 * (c2 + 1) / 2;
        int j = c2 * 64 + lane;
        float4 qj = QS[j];
        float  aj = AS[j];
        unsigned long long w = 0ull;
        if (cc == c2) {
            unsigned long long myrow = 0ull;
            for (int t = 0; t < 64; ++t) {
                float4 qt = QS[cc * 64 + t];
                float  at = AS[cc * 64 + t];
                float iw = fmaxf(fminf(qj.z, qt.z) - fmaxf(qj.x, qt.x), 0.0f);
                float ih = fmaxf(fminf(qj.w, qt.w) - fmaxf(qj.y, qt.y), 0.0f);
                float inter = iw * ih;
                float denom = (aj + at) - inter;
                bool supp = (fma((double)denom, MID_CONST,
                                 -(double)inter) <= 0.0) && (t < lane);
                unsigned long long bb2 = __ballot(supp);
                w |= supp ? (1ull << t) : 0ull;
                if (lane == t) myrow = bb2;
            }
            drow_g[((size_t)b * NCHUNK + cc) * 64 + lane] = myrow;
        } else {
#pragma unroll 8
            for (int t = 0; t < 64; ++t) {
                float4 qt = QS[cc * 64 + t];
                float  at = AS[cc * 64 + t];
                float iw = fmaxf(fminf(qj.z, qt.z) - fmaxf(qj.x, qt.x), 0.0f);
                float ih = fmaxf(fminf(qj.w, qt.w) - fmaxf(qj.y, qt.y), 0.0f);
                float inter = iw * ih;
                float denom = (aj + at) - inter;
                bool supp = (fma((double)denom, MID_CONST,
                                 -(double)inter) <= 0.0);
                w |= supp ? (1ull << t) : 0ull;
            }
        }
        sup_g[((size_t)b * NCHUNK + cc) * MCAP + j] = w;
    }
}

// ---------------------------------------------------------------------------
// Kernel 3b (tier 3): fused scan + epilogue. 256 threads/image. 4 waves stage
// SUP (128 KB) + DROW (8 KB) + sobj (8 KB) into LDS; wave 0 scans from LDS
// and zeroes suppressed sobj_l entries; then all waves run the epilogue from
// detws (coalesced) writing det (coalesced). 144 KB LDS -> 1 block/CU.
// ---------------------------------------------------------------------------
__global__ __launch_bounds__(256) void scanepi3_kernel(
    float* __restrict__ det,
    const float* __restrict__ detws,
    const float* __restrict__ sobj_g,
    const int* __restrict__ nobj_g,
    const unsigned long long* __restrict__ sup_g,
    const unsigned long long* __restrict__ drow_g)
{
#pragma clang fp contract(off)
    __shared__ unsigned long long SUPL[NCHUNK][MCAP];    // 128 KB
    __shared__ unsigned long long DR[NCHUNK][64];        // 8 KB
    __shared__ float sobj_l[NPAD];                       // 8 KB
    const int b = blockIdx.x;
    const int tid = threadIdx.x;
    const int lane = tid & 63;
    float* detb = det + (size_t)b * NBOX * 7;
    const float* dws = detws + (size_t)b * NBOX * 7;
    const int num_obj = nobj_g[b];
    const int M = (num_obj < MCAP) ? num_obj : MCAP;

    // stage sobj
#pragma unroll
    for (int c = 0; c < 8; ++c)
        sobj_l[tid + c * 256] = sobj_g[b * NPAD + tid + c * 256];

    if (num_obj <= MCAP) {
        const unsigned long long* supb = sup_g + (size_t)b * NCHUNK * MCAP;
#pragma unroll
        for (int i = 0; i < 64; ++i)
            ((unsigned long long*)SUPL)[tid + i * 256] = supb[tid + i * 256];
#pragma unroll
        for (int i = 0; i < 4; ++i)
            ((unsigned long long*)DR)[tid + i * 256] =
                drow_g[(size_t)b * NCHUNK * 64 + tid + i * 256];
        __syncthreads();

        if (tid < 64) {
            unsigned rm = 0u;                  // bit c = my box in chunk c dead
            for (int c = 0; c < NCHUNK && c * 64 < M; ++c) {
                int rem_in = M - c * 64;
                unsigned long long cmask =
                    (rem_in >= 64) ? ~0ull : ((1ull << rem_in) - 1ull);
                unsigned long long deadw = __ballot((rm >> c) & 1u);
                unsigned long long rowreg = DR[c][lane];
                unsigned long long rem = cmask & ~deadw;
                const unsigned long long rem0 = rem;
                unsigned long long S = 0ull;   // survivors of chunk c
                while (rem) {
                    int t = (int)__builtin_ctzll(rem);
                    S |= (1ull << t);
                    unsigned long long row_t = bcast64(rowreg, t);
                    rem &= ~row_t;
                    rem &= ~(1ull << t);
                }
                unsigned long long deadnew = rem0 & ~S;
                rm |= (unsigned)((deadnew >> lane) & 1ull) << c;
                for (int c2 = c + 1; c2 < NCHUNK && c2 * 64 < M; ++c2) {
                    unsigned long long w2 = SUPL[c][c2 * 64 + lane];
                    rm |= ((w2 & S) != 0ull) ? (1u << c2) : 0u;
                }
            }
#pragma unroll
            for (int c2 = 0; c2 < NCHUNK; ++c2) {
                int j = c2 * 64 + lane;
                if (j < M && ((rm >> c2) & 1u)) sobj_l[j] = 0.0f;
            }
        }
        __syncthreads();
    } else {
        __syncthreads();
        // fallback: serial greedy over coalesced sorted rows
        for (int i = 0; i < num_obj; ++i) {
            if (sobj_l[i] > 0.01f) {
                const float* ri = dws + i * 7;
                float bxi = ri[1], byi = ri[2], bwi = ri[3], bhi = ri[4];
                float xi1 = bxi - 0.5f * bwi, xi2 = bxi + 0.5f * bwi;
                float yi1 = byi - 0.5f * bhi, yi2 = byi + 0.5f * bhi;
                float ai = bwi * bhi;
                for (int j = i + 1 + tid; j < num_obj; j += 256) {
                    const float* rj = dws + j * 7;
                    float bxj = rj[1], byj = rj[2], bwj = rj[3], bhj = rj[4];
                    float x1j = bxj - 0.5f * bwj, x2j = bxj + 0.5f * bwj;
                    float y1j = byj - 0.5f * bhj, y2j = byj + 0.5f * bhj;
                    float aj = bwj * bhj;
                    float iw = fmaxf(fminf(x2j, xi2) - fmaxf(x1j, xi1), 0.0f);
                    float ih = fmaxf(fminf(y2j, yi2) - fmaxf(y1j, yi1), 0.0f);
                    float inter = iw * ih;
                    float iou = inter / ((aj + ai) - inter);
                    if (iou >= 0.45f) sobj_l[j] = 0.0f;
                }
            }
            __syncthreads();
        }
    }

    // --- epilogue: rows in sorted order from detws -> det (both coalesced) ---
#pragma unroll
    for (int c = 0; c < 8; ++c) {
        int r = tid + c * 256;
        if (r < NBOX) {
            const float* src = dws + r * 7;
            float obj = src[0], bx = src[1], by = src[2], bw = src[3];
            float bh = src[4], cid = src[5], prob = src[6];
            float s = sobj_l[r];
            bool keep = (r < num_obj) && (s > 0.01f) && (r != num_obj - 1);
            float p = prob * ((prob > 0.1f) ? 1.0f : 0.0f);
            bool fin = keep && (p > 0.01f) && (bw * bw > 0.0004f);
            float m = fin ? 1.0f : 0.0f;
            float* o = detb + r * 7;
            o[0] = obj * m; o[1] = bx * m; o[2] = by * m; o[3] = bw * m;
            o[4] = bh * m; o[5] = cid * m; o[6] = p * m;
        }
    }
}

// ---------------------------------------------------------------------------
// Tier-2 fused scan+epilogue (round 11) -- kept for 19.3MB <= ws < 25.8MB.
// ---------------------------------------------------------------------------
__global__ __launch_bounds__(256) void scanepi_kernel(
    float* __restrict__ det,
    const unsigned short* __restrict__ order_g,
    const float* __restrict__ sobj_g,
    const int* __restrict__ nobj_g,
    const unsigned long long* __restrict__ sup_g,
    const unsigned long long* __restrict__ drow_g)
{
#pragma clang fp contract(off)
    __shared__ float sobj_l[NPAD];
    __shared__ unsigned long long DR[NCHUNK][64];
    const int b = blockIdx.x;
    const int tid = threadIdx.x;
    const int lane = tid & 63;
    float* detb = det + (size_t)b * NBOX * 7;
    const unsigned short* ord = order_g + b * NPAD;
    const int num_obj = nobj_g[b];
    const int M = (num_obj < MCAP) ? num_obj : MCAP;

#pragma unroll
    for (int c = 0; c < 8; ++c) sobj_l[tid + c * 256] = sobj_g[b * NPAD + tid + c * 256];
    if (num_obj <= MCAP) {
#pragma unroll
        for (int c = 0; c < 4; ++c) {
            int i = tid + c * 256;
            ((unsigned long long*)DR)[i] = drow_g[(size_t)b * NCHUNK * 64 + i];
        }
    }
    __syncthreads();

    if (num_obj <= MCAP) {
        if (tid < 64) {
            unsigned rm = 0u;
            for (int c = 0; c < NCHUNK && c * 64 < M; ++c) {
                int rem_in = M - c * 64;
                unsigned long long cmask =
                    (rem_in >= 64) ? ~0ull : ((1ull << rem_in) - 1ull);
                unsigned long long deadw = __ballot((rm >> c) & 1u);
                unsigned long long rowreg = DR[c][lane];
                unsigned long long rem = cmask & ~deadw;
                const unsigned long long rem0 = rem;
                unsigned long long S = 0ull;
                while (rem) {
                    int t = (int)__builtin_ctzll(rem);
                    S |= (1ull << t);
                    unsigned long long row_t = bcast64(rowreg, t);
                    rem &= ~row_t;
                    rem &= ~(1ull << t);
                }
                unsigned long long deadnew = rem0 & ~S;
                rm |= (unsigned)((deadnew >> lane) & 1ull) << c;
                const unsigned long long* supc =
                    sup_g + ((size_t)b * NCHUNK + c) * MCAP;
                for (int c2 = c + 1; c2 < NCHUNK && c2 * 64 < M; ++c2) {
                    unsigned long long w2 = supc[c2 * 64 + lane];
                    rm |= ((w2 & S) != 0ull) ? (1u << c2) : 0u;
                }
            }
#pragma unroll
            for (int c2 = 0; c2 < NCHUNK; ++c2) {
                int j = c2 * 64 + lane;
                if (j < M && ((rm >> c2) & 1u)) sobj_l[j] = 0.0f;
            }
        }
        __syncthreads();
    } else {
        for (int i = 0; i < num_obj; ++i) {
            if (sobj_l[i] > 0.01f) {
                const float* ri = detb + (int)ord[i] * 7;
                float bxi = ri[1], byi = ri[2], bwi = ri[3], bhi = ri[4];
                float xi1 = bxi - 0.5f * bwi, xi2 = bxi + 0.5f * bwi;
                float yi1 = byi - 0.5f * bhi, yi2 = byi + 0.5f * bhi;
                float ai = bwi * bhi;
                for (int j = i + 1 + tid; j < num_obj; j += 256) {
                    const float* rj = detb + (int)ord[j] * 7;
                    float bxj = rj[1], byj = rj[2], bwj = rj[3], bhj = rj[4];
                    float x1j = bxj - 0.5f * bwj, x2j = bxj + 0.5f * bwj;
                    float y1j = byj - 0.5f * bhj, y2j = byj + 0.5f * bhj;
                    float aj = bwj * bhj;
                    float iw = fmaxf(fminf(x2j, xi2) - fmaxf(x1j, xi1), 0.0f);
                    float ih = fmaxf(fminf(y2j, yi2) - fmaxf(y1j, yi1), 0.0f);
                    float inter = iw * ih;
                    float iou = inter / ((aj + ai) - inter);
                    if (iou >= 0.45f) sobj_l[j] = 0.0f;
                }
            }
            __syncthreads();
        }
    }

    float v0[8], v1[8], v2[8], v3[8], v4[8], v5[8], v6[8], msk[8];
#pragma unroll
    for (int c = 0; c < 8; ++c) {
        int r = tid + c * 256;
        if (r < NBOX) {
            const float* row = detb + (int)ord[r] * 7;
            float obj = row[0], bx = row[1], by = row[2], bw = row[3];
            float bh = row[4], cid = row[5], prob = row[6];
            bool keep = (r < num_obj) && (sobj_l[r] > 0.01f) && (r != num_obj - 1);
            float p = prob * ((prob > 0.1f) ? 1.0f : 0.0f);
            bool fin = keep && (p > 0.01f) && (bw * bw > 0.0004f);
            v0[c] = obj; v1[c] = bx; v2[c] = by; v3[c] = bw; v4[c] = bh;
            v5[c] = cid; v6[c] = p;
            msk[c] = fin ? 1.0f : 0.0f;
        }
    }
    __syncthreads();
#pragma unroll
    for (int c = 0; c < 8; ++c) {
        int r = tid + c * 256;
        if (r < NBOX) {
            float* o = detb + r * 7;
            o[0] = v0[c] * msk[c]; o[1] = v1[c] * msk[c]; o[2] = v2[c] * msk[c];
            o[3] = v3[c] * msk[c]; o[4] = v4[c] * msk[c]; o[5] = v5[c] * msk[c];
            o[6] = v6[c] * msk[c];
        }
    }
}

// ---------------------------------------------------------------------------
// Tier-1 fallback (1.5MB <= ws < 19.3MB): monolithic two-phase NMS + epi.
// ---------------------------------------------------------------------------
__global__ __launch_bounds__(1024, 1) void nms4_kernel(
    const float* __restrict__ det,
    const unsigned short* __restrict__ order_g,
    float* __restrict__ sobj_g,
    const int* __restrict__ nobj_g)
{
#pragma clang fp contract(off)
    __shared__ float4 QS[MCAP];
    __shared__ float  AS[MCAP];
    __shared__ unsigned long long SUP[NCHUNK][MCAP];
    __shared__ unsigned long long DROW[NCHUNK][64];
    const int b = blockIdx.x;
    const int tid = threadIdx.x;
    const int lane = tid & 63;
    const int wv = tid >> 6;
    const float* detb = det + (size_t)b * NBOX * 7;
    const unsigned short* ord = order_g + b * NPAD;
    float* sobj = sobj_g + b * NPAD;
    const int num_obj = nobj_g[b];
    const int M = (num_obj < MCAP) ? num_obj : MCAP;

    if (num_obj <= MCAP) {
        {
            const float* row = detb + (int)ord[tid] * 7;
            float bx = row[1], by = row[2], bw = row[3], bh = row[4];
            QS[tid] = make_float4(bx - 0.5f * bw, by - 0.5f * bh,
                                  bx + 0.5f * bw, by + 0.5f * bh);
            AS[tid] = bw * bh;
        }
        __syncthreads();

        for (int k = wv; k < 136; k += 16) {
            int c2 = 0;
            while ((c2 + 1) * (c2 + 2) / 2 <= k) ++c2;
            int cc = k - c2 * (c2 + 1) / 2;
            if (c2 * 64 < M) {
                int j = c2 * 64 + lane;
                float4 qj = QS[j];
                float  aj = AS[j];
                unsigned long long w = 0ull;
                if (cc == c2) {
                    unsigned long long myrow = 0ull;
                    for (int t = 0; t < 64; ++t) {
                        float4 qt = QS[cc * 64 + t];
                        float  at = AS[cc * 64 + t];
                        float iw = fmaxf(fminf(qj.z, qt.z) - fmaxf(qj.x, qt.x), 0.0f);
                        float ih = fmaxf(fminf(qj.w, qt.w) - fmaxf(qj.y, qt.y), 0.0f);
                        float inter = iw * ih;
                        float denom = (aj + at) - inter;
                        bool supp = (fma((double)denom, MID_CONST,
                                         -(double)inter) <= 0.0) && (t < lane);
                        unsigned long long bb = __ballot(supp);
                        w |= supp ? (1ull << t) : 0ull;
                        if (lane == t) myrow = bb;
                    }
                    DROW[cc][lane] = myrow;
                } else {
#pragma unroll 8
                    for (int t = 0; t < 64; ++t) {
                        float4 qt = QS[cc * 64 + t];
                        float  at = AS[cc * 64 + t];
                        float iw = fmaxf(fminf(qj.z, qt.z) - fmaxf(qj.x, qt.x), 0.0f);
                        float ih = fmaxf(fminf(qj.w, qt.w) - fmaxf(qj.y, qt.y), 0.0f);
                        float inter = iw * ih;
                        float denom = (aj + at) - inter;
                        bool supp = (fma((double)denom, MID_CONST,
                                         -(double)inter) <= 0.0);
                        w |= supp ? (1ull << t) : 0ull;
                    }
                }
                SUP[cc][j] = w;
            }
        }
        __syncthreads();

        if (wv == 0) {
            unsigned rm = 0u;
            for (int c = 0; c < NCHUNK && c * 64 < M; ++c) {
                int rem_in = M - c * 64;
                unsigned long long cmask =
                    (rem_in >= 64) ? ~0ull : ((1ull << rem_in) - 1ull);
                unsigned long long deadw = __ballot((rm >> c) & 1u);
                unsigned long long rowreg = DROW[c][lane];
                unsigned long long rem = cmask & ~deadw;
                const unsigned long long rem0 = rem;
                unsigned long long S = 0ull;
                while (rem) {
                    int t = (int)__builtin_ctzll(rem);
                    S |= (1ull << t);
                    unsigned long long row_t = bcast64(rowreg, t);
                    rem &= ~row_t;
                    rem &= ~(1ull << t);
                }
                unsigned long long deadnew = rem0 & ~S;
                rm |= (unsigned)((deadnew >> lane) & 1ull) << c;
                for (int c2 = c + 1; c2 < NCHUNK && c2 * 64 < M; ++c2) {
                    unsigned long long w2 = SUP[c][c2 * 64 + lane];
                    rm |= ((w2 & S) != 0ull) ? (1u << c2) : 0u;
                }
            }
            for (int c2 = 0; c2 < NCHUNK; ++c2) {
                int j = c2 * 64 + lane;
                if (j < M && ((rm >> c2) & 1u)) sobj[j] = 0.0f;
            }
        }
    } else {
        for (int i = 0; i < num_obj; ++i) {
            if (sobj[i] > 0.01f) {
                const float* ri = detb + (int)ord[i] * 7;
                float bxi = ri[1], byi = ri[2], bwi = ri[3], bhi = ri[4];
                float xi1 = bxi - 0.5f * bwi, xi2 = bxi + 0.5f * bwi;
                float yi1 = byi - 0.5f * bhi, yi2 = byi + 0.5f * bhi;
                float ai = bwi * bhi;
                for (int j = i + 1 + tid; j < num_obj; j += 1024) {
                    const float* rj = detb + (int)ord[j] * 7;
                    float bxj = rj[1], byj = rj[2], bwj = rj[3], bhj = rj[4];
                    float x1j = bxj - 0.5f * bwj, x2j = bxj + 0.5f * bwj;
                    float y1j = byj - 0.5f * bhj, y2j = byj + 0.5f * bhj;
                    float aj = bwj * bhj;
                    float iw = fmaxf(fminf(x2j, xi2) - fmaxf(x1j, xi1), 0.0f);
                    float ih = fmaxf(fminf(y2j, yi2) - fmaxf(y1j, yi1), 0.0f);
                    float inter = iw * ih;
                    float iou = inter / ((aj + ai) - inter);
                    if (iou >= 0.45f) sobj[j] = 0.0f;
                }
            }
            __syncthreads();
        }
    }
}

__global__ __launch_bounds__(256) void epi_kernel(
    float* __restrict__ det,
    const unsigned short* __restrict__ order_g,
    const float* __restrict__ sobj_g,
    const int* __restrict__ nobj_g)
{
#pragma clang fp contract(off)
    const int b = blockIdx.x;
    const int tid = threadIdx.x;
    float* detb = det + (size_t)b * NBOX * 7;
    const unsigned short* ord = order_g + b * NPAD;
    const float* sobj = sobj_g + b * NPAD;
    const int num_obj = nobj_g[b];

    float v0[8], v1[8], v2[8], v3[8], v4[8], v5[8], v6[8], msk[8];
#pragma unroll
    for (int c = 0; c < 8; ++c) {
        int r = tid + c * 256;
        if (r < NBOX) {
            const float* row = detb + (int)ord[r] * 7;
            float obj = row[0], bx = row[1], by = row[2], bw = row[3];
            float bh = row[4], cid = row[5], prob = row[6];
            bool keep = (r < num_obj) && (sobj[r] > 0.01f) && (r != num_obj - 1);
            float p = prob * ((prob > 0.1f) ? 1.0f : 0.0f);
            bool fin = keep && (p > 0.01f) && (bw * bw > 0.0004f);
            v0[c] = obj; v1[c] = bx; v2[c] = by; v3[c] = bw; v4[c] = bh;
            v5[c] = cid; v6[c] = p;
            msk[c] = fin ? 1.0f : 0.0f;
        }
    }
    __syncthreads();
#pragma unroll
    for (int c = 0; c < 8; ++c) {
        int r = tid + c * 256;
        if (r < NBOX) {
            float* o = detb + r * 7;
            o[0] = v0[c] * msk[c];
            o[1] = v1[c] * msk[c];
            o[2] = v2[c] * msk[c];
            o[3] = v3[c] * msk[c];
            o[4] = v4[c] * msk[c];
            o[5] = v5[c] * msk[c];
            o[6] = v6[c] * msk[c];
        }
    }
}

// ---------------------------------------------------------------------------
// Last-resort monolithic kernel (ws < WS_NEEDED).
// ---------------------------------------------------------------------------
__global__ __launch_bounds__(K2T, 1) void nms_kernel(float* __restrict__ det)
{
#pragma clang fp contract(off)
    __shared__ alignas(16) unsigned long long keys[NPAD];
    __shared__ float s_obj[NBOX];
    __shared__ unsigned short order[NBOX];
    __shared__ int num_obj_sh;

    const int b = blockIdx.x;
    const int tid = threadIdx.x;
    float* detb = det + (size_t)b * NBOX * 7;

    for (int n = tid; n < NPAD; n += K2T) {
        if (n < NBOX) {
            unsigned ob = __float_as_uint(detb[n * 7 + 0]);
            keys[n] = ((unsigned long long)ob << 32) | (unsigned long long)(2047 - n);
        } else keys[n] = 0ull;
    }
    if (tid == 0) num_obj_sh = 0;
    __syncthreads();

    for (unsigned k = 2; k <= NPAD; k <<= 1) {
        for (unsigned j = k >> 1; j > 0; j >>= 1) {
            for (unsigned idx = tid; idx < NPAD; idx += K2T) {
                unsigned ixj = idx ^ j;
                if (ixj > idx) {
                    unsigned long long av = keys[idx], bv = keys[ixj];
                    bool up = ((idx & k) == 0);
                    if (up ? (av < bv) : (av > bv)) { keys[idx] = bv; keys[ixj] = av; }
                }
            }
            __syncthreads();
        }
    }

    int cnt = 0;
    for (int r = tid; r < NBOX; r += K2T) {
        unsigned long long kk = keys[r];
        order[r] = (unsigned short)(2047u - (unsigned)(kk & 0xffffffffu));
        float ob = __uint_as_float((unsigned)(kk >> 32));
        s_obj[r] = ob;
        cnt += (ob > 0.5f) ? 1 : 0;
    }
    atomicAdd(&num_obj_sh, cnt);
    __syncthreads();
    const int num_obj = num_obj_sh;

    for (int i = 0; i < num_obj; ++i) {
        if (s_obj[i] > 0.01f) {
            const float* ri = detb + (int)order[i] * 7;
            float bxi = ri[1], byi = ri[2], bwi = ri[3], bhi = ri[4];
            float xi1 = bxi - 0.5f * bwi, xi2 = bxi + 0.5f * bwi;
            float yi1 = byi - 0.5f * bhi, yi2 = byi + 0.5f * bhi;
            float ai = bwi * bhi;
            for (int j = i + 1 + tid; j < num_obj; j += K2T) {
                const float* rj = detb + (int)order[j] * 7;
                float bxj = rj[1], byj = rj[2], bwj = rj[3], bhj = rj[4];
                float x1j = bxj - 0.5f * bwj, x2j = bxj + 0.5f * bwj;
                float y1j = byj - 0.5f * bhj, y2j = byj + 0.5f * bhj;
                float aj = bwj * bhj;
                float iw = fmaxf(fminf(x2j, xi2) - fmaxf(x1j, xi1), 0.0f);
                float ih = fmaxf(fminf(y2j, yi2) - fmaxf(y1j, yi1), 0.0f);
                float inter = iw * ih;
                float iou = inter / ((aj + ai) - inter);
                if (iou >= 0.45f) s_obj[j] = 0.0f;
            }
        }
        __syncthreads();
    }

    float v0[8], v1[8], v2[8], v3[8], v4[8], v5[8], v6[8], msk[8];
#pragma unroll
    for (int c = 0; c < 8; ++c) {
        int r = tid + c * K2T;
        if (r < NBOX) {
            const float* row = detb + (int)order[r] * 7;
            float obj = row[0], bx = row[1], by = row[2], bw = row[3];
            float bh = row[4], cid = row[5], prob = row[6];
            bool keep = (r < num_obj) && (s_obj[r] > 0.01f) && (r != num_obj - 1);
            float p = prob * ((prob > 0.1f) ? 1.0f : 0.0f);
            bool fin = keep && (p > 0.01f) && (bw * bw > 0.0004f);
            v0[c] = obj; v1[c] = bx; v2[c] = by; v3[c] = bw; v4[c] = bh;
            v5[c] = cid; v6[c] = p;
            msk[c] = fin ? 1.0f : 0.0f;
        }
    }
    __syncthreads();
#pragma unroll
    for (int c = 0; c < 8; ++c) {
        int r = tid + c * K2T;
        if (r < NBOX) {
            float* o = detb + r * 7;
            o[0] = v0[c] * msk[c]; o[1] = v1[c] * msk[c]; o[2] = v2[c] * msk[c];
            o[3] = v3[c] * msk[c]; o[4] = v4[c] * msk[c]; o[5] = v5[c] * msk[c];
            o[6] = v6[c] * msk[c];
        }
    }
}

extern "C" void kernel_launch(void* const* d_in, const int* in_sizes, int n_in,
                              void* d_out, int out_size, void* d_ws, size_t ws_size,
                              hipStream_t stream)
{
    const float* pred    = (const float*)d_in[0];
    const float* anchors = (const float*)d_in[1];
    float* out = (float*)d_out;

    int total = NBATCH * NBOX;
    int blocks = (total + 255) / 256;
    decode_kernel<<<blocks, 256, 0, stream>>>(pred, anchors, out);

    if (ws_size >= WS_NEEDED) {
        char* ws = (char*)d_ws;
        int*            nobj  = (int*)(ws + WS_NUMOBJ_OFF);
        unsigned short* order = (unsigned short*)(ws + WS_ORDER_OFF);
        float*          sobj  = (float*)(ws + WS_SOBJ_OFF);
        if (ws_size >= WS_NEEDED3) {
            unsigned long long* sup  = (unsigned long long*)(ws + WS_SUP_OFF);
            unsigned long long* drow = (unsigned long long*)(ws + WS_DROW_OFF);
            float*              detw = (float*)(ws + WS_DETW_OFF);
            sort_kernel<<<NBATCH, 1024, 0, stream>>>(out, order, sobj, nobj, detw);
            sup_kernel<<<NBATCH * NSPLIT, 1024, 0, stream>>>(out, order, nobj, sup, drow, detw);
            scanepi3_kernel<<<NBATCH, 256, 0, stream>>>(out, detw, sobj, nobj, sup, drow);
        } else if (ws_size >= WS_NEEDED2) {
            unsigned long long* sup  = (unsigned long long*)(ws + WS_SUP_OFF);
            unsigned long long* drow = (unsigned long long*)(ws + WS_DROW_OFF);
            sort_kernel<<<NBATCH, 1024, 0, stream>>>(out, order, sobj, nobj, nullptr);
            sup_kernel<<<NBATCH * NSPLIT, 1024, 0, stream>>>(out, order, nobj, sup, drow, nullptr);
            scanepi_kernel<<<NBATCH, 256, 0, stream>>>(out, order, sobj, nobj, sup, drow);
        } else {
            sort_kernel<<<NBATCH, 1024, 0, stream>>>(out, order, sobj, nobj, nullptr);
            nms4_kernel<<<NBATCH, 1024, 0, stream>>>(out, order, sobj, nobj);
            epi_kernel<<<NBATCH, 256, 0, stream>>>(out, order, sobj, nobj);
        }
    } else {
        nms_kernel<<<NBATCH, K2T, 0, stream>>>(out);
    }
}